// Round 2
// baseline (932.798 us; speedup 1.0000x reference)
//
#include <hip/hip_runtime.h>
#include <hip/hip_bf16.h>

// ---- problem constants ----
#define BSZ 2
#define LSEQ 1024
#define DMODEL 768
#define NLAYER 4
#define DINNER 1536
#define DSTATE 16
#define DCONV 4
#define DTRANK 48
#define NCHUNK 64
#define CLEN 16
#define XDSTR 128
#define XZLD (2 * DINNER)

typedef __bf16 bf16x8_t __attribute__((ext_vector_type(8)));
typedef float f32x4_t __attribute__((ext_vector_type(4)));
typedef unsigned short u16x8_t __attribute__((ext_vector_type(8)));
typedef __hip_bfloat16 bf16;

__device__ inline float bfbits2f(unsigned short u) {
    unsigned int x = ((unsigned int)u) << 16;
    return __builtin_bit_cast(float, x);
}
__device__ inline unsigned short f2bfbits(float f) {
    return __builtin_bit_cast(unsigned short, (__bf16)f);
}

__device__ inline float block_reduce_sum(float v, float* sbuf) {
    __syncthreads();
    #pragma unroll
    for (int o = 32; o > 0; o >>= 1) v += __shfl_down(v, o, 64);
    int wid = threadIdx.x >> 6;
    int lane = threadIdx.x & 63;
    if (lane == 0) sbuf[wid] = v;
    __syncthreads();
    if (threadIdx.x == 0) sbuf[0] = (sbuf[0] + sbuf[1]) + (sbuf[2] + sbuf[3]);
    __syncthreads();
    return sbuf[0];
}

// ---------------- init: weight prep f32->bf16 + embedding + xdbl zero ----------------
#define PN1 (NLAYER * 3072 * 768)
#define PN2 (NLAYER * 768 * 1536)
#define PN3 (NLAYER * 128 * 1536)
#define PN4 (BSZ * LSEQ * DMODEL)
#define PN5 (2 * BSZ * LSEQ * XDSTR)
// total = 14,942,208 + 1,572,864 + 524,288 = 17,039,360 -> grid 66560
__global__ __launch_bounds__(256) void init_kernel(
    const int* __restrict__ seq, const float* __restrict__ emb,
    const float* __restrict__ in_w, const float* __restrict__ out_w,
    const float* __restrict__ xp_w,
    float* __restrict__ residual, bf16* __restrict__ in16,
    bf16* __restrict__ out16, bf16* __restrict__ xp16, float* __restrict__ xdbl2) {
    int idx = blockIdx.x * 256 + threadIdx.x;
    if (idx < PN1) { in16[idx] = __float2bfloat16(in_w[idx]); return; }
    idx -= PN1;
    if (idx < PN2) { out16[idx] = __float2bfloat16(out_w[idx]); return; }
    idx -= PN2;
    if (idx < PN3) {
        int l = idx / (128 * DINNER);
        int r = idx - l * (128 * DINNER);
        int e = r / DINNER;
        int k = r - e * DINNER;
        xp16[idx] = (e < 80) ? __float2bfloat16(xp_w[((size_t)l * 80 + e) * DINNER + k])
                             : __float2bfloat16(0.f);
        return;
    }
    idx -= PN3;
    if (idx < PN4) {
        int bl = idx / DMODEL;
        int dd = idx - bl * DMODEL;
        residual[idx] = emb[(size_t)seq[bl] * DMODEL + dd];
        return;
    }
    idx -= PN4;
    xdbl2[idx] = 0.f;   // idx < PN5 guaranteed by grid size
}

// ---------------- rmsnorm -> bf16 ----------------
__global__ __launch_bounds__(256) void rmsnorm_kernel(
    const float* __restrict__ res, const float* __restrict__ w, bf16* __restrict__ out) {
    __shared__ float sbuf[8];
    int row = blockIdx.x;
    const float* x = res + (size_t)row * DMODEL;
    float ss = 0.f;
    for (int i = threadIdx.x; i < DMODEL; i += 256) { float v = x[i]; ss += v * v; }
    ss = block_reduce_sum(ss, sbuf);
    float scale = rsqrtf(ss / (float)DMODEL + 1e-5f);
    for (int i = threadIdx.x; i < DMODEL; i += 256)
        out[(size_t)row * DMODEL + i] = __float2bfloat16(x[i] * scale * w[i]);
}

// ---------------- GEMM 128x128 tile, bf16 in -> bf16 out (in_proj) ----------------
__global__ __launch_bounds__(256) void gemm_128x128(
    const bf16* __restrict__ A, int lda, const bf16* __restrict__ Bw, int ldb,
    bf16* __restrict__ C16, int ldc, int K) {
    __shared__ bf16 As[128][72];
    __shared__ bf16 Bs[128][72];
    int tid = threadIdx.x;
    int wave = tid >> 6;
    int lane = tid & 63;
    int quad = lane >> 4;
    int l16 = lane & 15;
    int bm = blockIdx.x * 128;
    int bn = blockIdx.y * 128;
    int wm = (wave >> 1) * 64;
    int wn = (wave & 1) * 64;
    int srow = tid >> 1, sk = (tid & 1) * 32;

    f32x4_t acc[4][4];
    #pragma unroll
    for (int i = 0; i < 4; ++i)
        #pragma unroll
        for (int j = 0; j < 4; ++j) acc[i][j] = (f32x4_t){0.f, 0.f, 0.f, 0.f};

    for (int k0 = 0; k0 < K; k0 += 64) {
        const bf16* ag = A + (size_t)(bm + srow) * lda + k0 + sk;
        const bf16* bg = Bw + (size_t)(bn + srow) * ldb + k0 + sk;
        *(int4*)&As[srow][sk]      = *(const int4*)(ag);
        *(int4*)&As[srow][sk + 8]  = *(const int4*)(ag + 8);
        *(int4*)&As[srow][sk + 16] = *(const int4*)(ag + 16);
        *(int4*)&As[srow][sk + 24] = *(const int4*)(ag + 24);
        *(int4*)&Bs[srow][sk]      = *(const int4*)(bg);
        *(int4*)&Bs[srow][sk + 8]  = *(const int4*)(bg + 8);
        *(int4*)&Bs[srow][sk + 16] = *(const int4*)(bg + 16);
        *(int4*)&Bs[srow][sk + 24] = *(const int4*)(bg + 24);
        __syncthreads();
        #pragma unroll
        for (int kk = 0; kk < 64; kk += 32) {
            bf16x8_t af[4], bf[4];
            #pragma unroll
            for (int i = 0; i < 4; ++i)
                af[i] = *(const bf16x8_t*)(&As[wm + i * 16 + l16][kk + quad * 8]);
            #pragma unroll
            for (int j = 0; j < 4; ++j)
                bf[j] = *(const bf16x8_t*)(&Bs[wn + j * 16 + l16][kk + quad * 8]);
            #pragma unroll
            for (int i = 0; i < 4; ++i)
                #pragma unroll
                for (int j = 0; j < 4; ++j)
                    acc[i][j] = __builtin_amdgcn_mfma_f32_16x16x32_bf16(af[i], bf[j], acc[i][j], 0, 0, 0);
        }
        __syncthreads();
    }

    int mbase = bm + wm + quad * 4;
    #pragma unroll
    for (int i = 0; i < 4; ++i)
        #pragma unroll
        for (int j = 0; j < 4; ++j) {
            int n = bn + wn + j * 16 + l16;
            #pragma unroll
            for (int r = 0; r < 4; ++r)
                C16[(size_t)(mbase + i * 16 + r) * ldc + n] = __float2bfloat16(acc[i][j][r]);
        }
}

// ---------------- GEMM 128x64 tile, bf16 in, direct f32 += out (out_proj) ----------------
__global__ __launch_bounds__(256) void gemm_128x64_add(
    const bf16* __restrict__ A, int lda, const bf16* __restrict__ Bw, int ldb,
    float* __restrict__ Cf, int ldc, int K) {
    __shared__ bf16 As[128][72];
    __shared__ bf16 Bs[64][72];
    int tid = threadIdx.x;
    int wave = tid >> 6;
    int lane = tid & 63;
    int quad = lane >> 4;
    int l16 = lane & 15;
    int bm = blockIdx.x * 128;
    int bn = blockIdx.y * 64;
    int wm = wave * 32;
    int arow = tid >> 1, ak = (tid & 1) * 32;
    int brow = tid >> 2, bk = (tid & 3) * 16;

    f32x4_t acc[2][4];
    #pragma unroll
    for (int i = 0; i < 2; ++i)
        #pragma unroll
        for (int j = 0; j < 4; ++j) acc[i][j] = (f32x4_t){0.f, 0.f, 0.f, 0.f};

    for (int k0 = 0; k0 < K; k0 += 64) {
        const bf16* ag = A + (size_t)(bm + arow) * lda + k0 + ak;
        const bf16* bg = Bw + (size_t)(bn + brow) * ldb + k0 + bk;
        *(int4*)&As[arow][ak]      = *(const int4*)(ag);
        *(int4*)&As[arow][ak + 8]  = *(const int4*)(ag + 8);
        *(int4*)&As[arow][ak + 16] = *(const int4*)(ag + 16);
        *(int4*)&As[arow][ak + 24] = *(const int4*)(ag + 24);
        *(int4*)&Bs[brow][bk]      = *(const int4*)(bg);
        *(int4*)&Bs[brow][bk + 8]  = *(const int4*)(bg + 8);
        __syncthreads();
        #pragma unroll
        for (int kk = 0; kk < 64; kk += 32) {
            bf16x8_t af[2], bf[4];
            #pragma unroll
            for (int i = 0; i < 2; ++i)
                af[i] = *(const bf16x8_t*)(&As[wm + i * 16 + l16][kk + quad * 8]);
            #pragma unroll
            for (int j = 0; j < 4; ++j)
                bf[j] = *(const bf16x8_t*)(&Bs[j * 16 + l16][kk + quad * 8]);
            #pragma unroll
            for (int i = 0; i < 2; ++i)
                #pragma unroll
                for (int j = 0; j < 4; ++j)
                    acc[i][j] = __builtin_amdgcn_mfma_f32_16x16x32_bf16(af[i], bf[j], acc[i][j], 0, 0, 0);
        }
        __syncthreads();
    }

    int mbase = bm + wm + quad * 4;
    #pragma unroll
    for (int i = 0; i < 2; ++i)
        #pragma unroll
        for (int j = 0; j < 4; ++j) {
            int n = bn + j * 16 + l16;
            #pragma unroll
            for (int r = 0; r < 4; ++r)
                Cf[(size_t)(mbase + i * 16 + r) * ldc + n] += acc[i][j][r];
        }
}

// ---------------- x_proj GEMM 64x64, conv+bias+silu fused into A staging ----------------
// A[row][d] = silu(cb[d] + sum_t xz16[row-3+t][d]*cw[d][t]);  split-K=4 atomic f32 out
#define XKPB 384
__global__ __launch_bounds__(256) void xproj_conv_gemm(
    const bf16* __restrict__ xz16, const float* __restrict__ cw, const float* __restrict__ cb,
    const bf16* __restrict__ Bw, float* __restrict__ Cf) {
    __shared__ bf16 As[64][72];
    __shared__ bf16 Bs[64][72];
    int tid = threadIdx.x;
    int wave = tid >> 6;
    int lane = tid & 63;
    int quad = lane >> 4;
    int l16 = lane & 15;
    int bm = blockIdx.x * 64;
    int bn = blockIdx.y * 64;
    int lrow = tid >> 2;
    int lk = (tid & 3) * 16;
    int kbeg = blockIdx.z * XKPB;
    int kend = kbeg + XKPB;
    int row = bm + lrow;
    int l = row & (LSEQ - 1);

    f32x4_t acc[4];
    #pragma unroll
    for (int i = 0; i < 4; ++i) acc[i] = (f32x4_t){0.f, 0.f, 0.f, 0.f};

    for (int k0 = kbeg; k0 < kend; k0 += 64) {
        int d0 = k0 + lk;
        // ---- A stage: conv4 + bias + silu from xz16 x-half ----
        u16x8_t xa[4][2];
        const u16x8_t Z8 = (u16x8_t){0, 0, 0, 0, 0, 0, 0, 0};
        #pragma unroll
        for (int t = 0; t < 4; ++t) {
            if (l >= 3 - t) {
                const u16x8_t* p = (const u16x8_t*)(xz16 + (size_t)(row - 3 + t) * XZLD + d0);
                xa[t][0] = p[0];
                xa[t][1] = p[1];
            } else { xa[t][0] = Z8; xa[t][1] = Z8; }
        }
        float cbv[16];
        #pragma unroll
        for (int q = 0; q < 4; ++q)
            *(float4*)&cbv[q * 4] = *(const float4*)(cb + d0 + q * 4);
        u16x8_t r0, r1;
        #pragma unroll
        for (int j = 0; j < 8; ++j) {
            float4 cwv = *(const float4*)(cw + (size_t)(d0 + j) * 4);
            float a = cbv[j]
                + bfbits2f(xa[0][0][j]) * cwv.x + bfbits2f(xa[1][0][j]) * cwv.y
                + bfbits2f(xa[2][0][j]) * cwv.z + bfbits2f(xa[3][0][j]) * cwv.w;
            a = a / (1.f + __expf(-a));
            r0[j] = f2bfbits(a);
        }
        #pragma unroll
        for (int j = 0; j < 8; ++j) {
            float4 cwv = *(const float4*)(cw + (size_t)(d0 + 8 + j) * 4);
            float a = cbv[8 + j]
                + bfbits2f(xa[0][1][j]) * cwv.x + bfbits2f(xa[1][1][j]) * cwv.y
                + bfbits2f(xa[2][1][j]) * cwv.z + bfbits2f(xa[3][1][j]) * cwv.w;
            a = a / (1.f + __expf(-a));
            r1[j] = f2bfbits(a);
        }
        *(u16x8_t*)&As[lrow][lk]     = r0;
        *(u16x8_t*)&As[lrow][lk + 8] = r1;
        // ---- B stage ----
        const bf16* bg = Bw + (size_t)(bn + lrow) * DINNER + d0;
        *(int4*)&Bs[lrow][lk]     = *(const int4*)(bg);
        *(int4*)&Bs[lrow][lk + 8] = *(const int4*)(bg + 8);
        __syncthreads();
        #pragma unroll
        for (int kk = 0; kk < 64; kk += 32) {
            bf16x8_t af = *(const bf16x8_t*)(&As[wave * 16 + l16][kk + quad * 8]);
            #pragma unroll
            for (int i = 0; i < 4; ++i) {
                bf16x8_t bv = *(const bf16x8_t*)(&Bs[i * 16 + l16][kk + quad * 8]);
                acc[i] = __builtin_amdgcn_mfma_f32_16x16x32_bf16(af, bv, acc[i], 0, 0, 0);
            }
        }
        __syncthreads();
    }

    int m0 = bm + wave * 16 + quad * 4;
    #pragma unroll
    for (int i = 0; i < 4; ++i) {
        int n = bn + i * 16 + l16;
        #pragma unroll
        for (int r = 0; r < 4; ++r)
            atomicAdd(&Cf[(size_t)(m0 + r) * XDSTR + n], acc[i][r]);
    }
}

// ---------------- delta from f32 xdbl row (wave-uniform) + per-thread dtw ----------------
__device__ inline float compute_delta(const float* __restrict__ xrow,
                                      const float* __restrict__ dtw, float dtbd) {
    float acc = dtbd;
    #pragma unroll
    for (int j = 0; j < DTRANK; j += 4) {
        float4 xv = *(const float4*)(xrow + j);
        acc += xv.x * dtw[j] + xv.y * dtw[j + 1] + xv.z * dtw[j + 2] + xv.w * dtw[j + 3];
    }
    return (acc > 20.f) ? acc : log1pf(__expf(acc));
}

// ================= chunked scan (dt + conv fused) =================
__global__ __launch_bounds__(256) void scan_phaseA(
    const bf16* __restrict__ xz16, const float* __restrict__ cw, const float* __restrict__ cb,
    const float* __restrict__ xdbl,
    const float* __restrict__ dt_w, const float* __restrict__ dt_b,
    const float* __restrict__ A_log,
    float* __restrict__ Psum, float* __restrict__ Ssum,
    float* __restrict__ xd_next) {
    int gtid = blockIdx.x * 256 + threadIdx.x;
    int d = gtid % DINNER;
    int c = (gtid / DINNER) % NCHUNK;
    int b = gtid / (DINNER * NCHUNK);
    float dtw[DTRANK];
    #pragma unroll
    for (int j = 0; j < DTRANK; j += 4)
        *(float4*)(dtw + j) = *(const float4*)(dt_w + (size_t)d * DTRANK + j);
    float dtbd = dt_b[d];
    float4 cwv = *(const float4*)(cw + (size_t)d * DCONV);
    float cbd = cb[d];
    float Av[DSTATE], P[DSTATE], S[DSTATE];
    #pragma unroll
    for (int s = 0; s < DSTATE; ++s) {
        Av[s] = -__expf(A_log[d * DSTATE + s]);
        P[s] = 1.f; S[s] = 0.f;
    }
    int t0 = c * CLEN;
    int rowb = b * LSEQ;
    float x3 = (t0 >= 3) ? __bfloat162float(xz16[(size_t)(rowb + t0 - 3) * XZLD + d]) : 0.f;
    float x2 = (t0 >= 2) ? __bfloat162float(xz16[(size_t)(rowb + t0 - 2) * XZLD + d]) : 0.f;
    float x1 = (t0 >= 1) ? __bfloat162float(xz16[(size_t)(rowb + t0 - 1) * XZLD + d]) : 0.f;
    for (int i = 0; i < CLEN; ++i) {
        int row = rowb + t0 + i;
        const float* xrow = xdbl + (size_t)row * XDSTR;
        float dl = compute_delta(xrow, dtw, dtbd);
        float x0 = __bfloat162float(xz16[(size_t)row * XZLD + d]);
        float ur = cbd + x3 * cwv.x + x2 * cwv.y + x1 * cwv.z + x0 * cwv.w;
        float u = ur / (1.f + __expf(-ur));
        x3 = x2; x2 = x1; x1 = x0;
        float bt = dl * u;
        const float4* Bp = (const float4*)(xrow + DTRANK);
        float4 B0 = Bp[0], B1 = Bp[1], B2 = Bp[2], B3 = Bp[3];
        float Bv[DSTATE] = {B0.x,B0.y,B0.z,B0.w, B1.x,B1.y,B1.z,B1.w,
                            B2.x,B2.y,B2.z,B2.w, B3.x,B3.y,B3.z,B3.w};
        #pragma unroll
        for (int s = 0; s < DSTATE; ++s) {
            float a = __expf(dl * Av[s]);
            P[s] *= a;
            S[s] = a * S[s] + bt * Bv[s];
        }
    }
    size_t base = ((size_t)(b * NCHUNK + c) * DSTATE) * DINNER + d;
    #pragma unroll
    for (int s = 0; s < DSTATE; ++s) {
        Psum[base + (size_t)s * DINNER] = P[s];
        Ssum[base + (size_t)s * DINNER] = S[s];
    }
    // zero next layer's xdbl buffer (its last reader finished 2+ kernels ago)
    for (int z = gtid; z < BSZ * LSEQ * XDSTR; z += BSZ * NCHUNK * DINNER)
        xd_next[z] = 0.f;
}

__global__ __launch_bounds__(256) void scan_phaseB(
    const float* __restrict__ Psum, const float* __restrict__ Ssum,
    float* __restrict__ Hin) {
    int gtid = blockIdx.x * 256 + threadIdx.x;
    int d = gtid % DINNER;
    int s = (gtid / DINNER) % DSTATE;
    int b = gtid / (DINNER * DSTATE);
    float h = 0.f;
    for (int c = 0; c < NCHUNK; ++c) {
        size_t idx = ((size_t)(b * NCHUNK + c) * DSTATE + s) * DINNER + d;
        Hin[idx] = h;
        h = Psum[idx] * h + Ssum[idx];
    }
}

__global__ __launch_bounds__(256) void scan_phaseC(
    const bf16* __restrict__ xz16, const float* __restrict__ cw, const float* __restrict__ cb,
    const float* __restrict__ xdbl,
    const float* __restrict__ dt_w, const float* __restrict__ dt_b,
    const float* __restrict__ A_log, const float* __restrict__ D_skip,
    const float* __restrict__ Hin, bf16* __restrict__ y16) {
    int gtid = blockIdx.x * 256 + threadIdx.x;
    int d = gtid % DINNER;
    int c = (gtid / DINNER) % NCHUNK;
    int b = gtid / (DINNER * NCHUNK);
    float dtw[DTRANK];
    #pragma unroll
    for (int j = 0; j < DTRANK; j += 4)
        *(float4*)(dtw + j) = *(const float4*)(dt_w + (size_t)d * DTRANK + j);
    float dtbd = dt_b[d];
    float4 cwv = *(const float4*)(cw + (size_t)d * DCONV);
    float cbd = cb[d];
    float Av[DSTATE], h[DSTATE];
    size_t base = ((size_t)(b * NCHUNK + c) * DSTATE) * DINNER + d;
    #pragma unroll
    for (int s = 0; s < DSTATE; ++s) {
        Av[s] = -__expf(A_log[d * DSTATE + s]);
        h[s] = Hin[base + (size_t)s * DINNER];
    }
    float Dsk = D_skip[d];
    int t0 = c * CLEN;
    int rowb = b * LSEQ;
    float x3 = (t0 >= 3) ? __bfloat162float(xz16[(size_t)(rowb + t0 - 3) * XZLD + d]) : 0.f;
    float x2 = (t0 >= 2) ? __bfloat162float(xz16[(size_t)(rowb + t0 - 2) * XZLD + d]) : 0.f;
    float x1 = (t0 >= 1) ? __bfloat162float(xz16[(size_t)(rowb + t0 - 1) * XZLD + d]) : 0.f;
    for (int i = 0; i < CLEN; ++i) {
        int row = rowb + t0 + i;
        const float* xrow = xdbl + (size_t)row * XDSTR;
        float dl = compute_delta(xrow, dtw, dtbd);
        float x0 = __bfloat162float(xz16[(size_t)row * XZLD + d]);
        float ur = cbd + x3 * cwv.x + x2 * cwv.y + x1 * cwv.z + x0 * cwv.w;
        float u = ur / (1.f + __expf(-ur));
        x3 = x2; x2 = x1; x1 = x0;
        float bt = dl * u;
        const float4* Bp = (const float4*)(xrow + DTRANK);
        float4 B0 = Bp[0], B1 = Bp[1], B2 = Bp[2], B3 = Bp[3];
        const float4* Cp = (const float4*)(xrow + DTRANK + DSTATE);
        float4 C0 = Cp[0], C1 = Cp[1], C2 = Cp[2], C3 = Cp[3];
        float Bv[DSTATE] = {B0.x,B0.y,B0.z,B0.w, B1.x,B1.y,B1.z,B1.w,
                            B2.x,B2.y,B2.z,B2.w, B3.x,B3.y,B3.z,B3.w};
        float Cv[DSTATE] = {C0.x,C0.y,C0.z,C0.w, C1.x,C1.y,C1.z,C1.w,
                            C2.x,C2.y,C2.z,C2.w, C3.x,C3.y,C3.z,C3.w};
        float acc = 0.f;
        #pragma unroll
        for (int s = 0; s < DSTATE; ++s) {
            float a = __expf(dl * Av[s]);
            h[s] = a * h[s] + bt * Bv[s];
            acc += h[s] * Cv[s];
        }
        float zv = __bfloat162float(xz16[(size_t)row * XZLD + DINNER + d]);
        float sz = zv / (1.f + __expf(-zv));
        y16[(size_t)row * DINNER + d] = __float2bfloat16((acc + u * Dsk) * sz);
    }
}

// ---------------- final: last-token rmsnorm ----------------
__global__ __launch_bounds__(256) void final_kernel(
    const float* __restrict__ res, const int* __restrict__ mask,
    const float* __restrict__ w, float* __restrict__ out) {
    __shared__ float sbuf[8];
    int b = blockIdx.x;
    float cnt = 0.f;
    for (int i = threadIdx.x; i < LSEQ; i += 256) cnt += (float)mask[b * LSEQ + i];
    cnt = block_reduce_sum(cnt, sbuf);
    int last = (int)cnt - 1;
    const float* x = res + ((size_t)b * LSEQ + last) * DMODEL;
    float ss = 0.f;
    for (int i = threadIdx.x; i < DMODEL; i += 256) { float v = x[i]; ss += v * v; }
    ss = block_reduce_sum(ss, sbuf);
    float scale = rsqrtf(ss / (float)DMODEL + 1e-5f);
    for (int i = threadIdx.x; i < DMODEL; i += 256)
        out[b * DMODEL + i] = x[i] * scale * w[i];
}

extern "C" void kernel_launch(void* const* d_in, const int* in_sizes, int n_in,
                              void* d_out, int out_size, void* d_ws, size_t ws_size,
                              hipStream_t stream) {
    const int*   seq      = (const int*)d_in[0];
    const int*   mask     = (const int*)d_in[1];
    const float* emb      = (const float*)d_in[2];
    const float* norm_w   = (const float*)d_in[3];
    const float* in_w     = (const float*)d_in[4];
    const float* conv_w   = (const float*)d_in[5];
    const float* conv_b   = (const float*)d_in[6];
    const float* xp_w     = (const float*)d_in[7];
    const float* dt_w     = (const float*)d_in[8];
    const float* dt_b     = (const float*)d_in[9];
    const float* A_log    = (const float*)d_in[10];
    const float* D_skip   = (const float*)d_in[11];
    const float* out_w    = (const float*)d_in[12];
    const float* normf_w  = (const float*)d_in[13];
    float* out = (float*)d_out;

    char* ws = (char*)d_ws;
    float* residual = (float*)(ws);                      //  6,291,456
    bf16*  hn16     = (bf16*)(ws + 6291456);             //  3,145,728
    bf16*  xz16     = (bf16*)(ws + 9437184);             // 12,582,912
    float* xdbl     = (float*)(ws + 22020096);           //  2,097,152 (2 buffers)
    bf16*  ybuf16   = (bf16*)(ws + 24117248);            //  6,291,456
    float* Psum     = (float*)(ws + 30408704);           // 12,582,912
    float* Ssum     = (float*)(ws + 42991616);           // 12,582,912
    float* Hin      = (float*)(ws + 55574528);           // 12,582,912
    bf16*  in16     = (bf16*)(ws + 68157440);            // 18,874,368
    bf16*  out16    = (bf16*)(ws + 87031808);            //  9,437,184
    bf16*  xp16     = (bf16*)(ws + 96468992);            //  1,572,864
                                                         // total 98,041,856 bytes

    init_kernel<<<66560, 256, 0, stream>>>(seq, emb, in_w, out_w, xp_w,
                                           residual, in16, out16, xp16, xdbl);

    for (int i = 0; i < NLAYER; ++i) {
        float* xd_cur = xdbl + (size_t)(i & 1) * (BSZ * LSEQ * XDSTR);
        float* xd_nxt = xdbl + (size_t)((i + 1) & 1) * (BSZ * LSEQ * XDSTR);
        const float* cw = conv_w + (size_t)i * DINNER * DCONV;
        const float* cb = conv_b + (size_t)i * DINNER;
        const float* dw = dt_w + (size_t)i * DINNER * DTRANK;
        const float* db = dt_b + (size_t)i * DINNER;
        const float* al = A_log + (size_t)i * DINNER * DSTATE;

        rmsnorm_kernel<<<BSZ * LSEQ, 256, 0, stream>>>(residual, norm_w + (size_t)i * DMODEL, hn16);
        // in_proj: xz16(2048x3072) = hn16 @ in16[i]^T
        gemm_128x128<<<dim3(16, 24), 256, 0, stream>>>(
            hn16, DMODEL, in16 + (size_t)i * 3072 * DMODEL, DMODEL, xz16, XZLD, DMODEL);
        // x_proj (conv+silu fused into A staging): xdbl(2048x128) f32, split-K=4 atomic
        xproj_conv_gemm<<<dim3(32, 2, 4), 256, 0, stream>>>(
            xz16, cw, cb, xp16 + (size_t)i * 128 * DINNER, xd_cur);
        scan_phaseA<<<768, 256, 0, stream>>>(
            xz16, cw, cb, xd_cur, dw, db, al, Psum, Ssum, xd_nxt);
        scan_phaseB<<<192, 256, 0, stream>>>(Psum, Ssum, Hin);
        scan_phaseC<<<768, 256, 0, stream>>>(
            xz16, cw, cb, xd_cur, dw, db, al, D_skip + (size_t)i * DINNER, Hin, ybuf16);
        // out_proj: residual += ybuf16 @ out16[i]^T  (direct, single-writer)
        gemm_128x64_add<<<dim3(16, 12), 256, 0, stream>>>(
            ybuf16, DINNER, out16 + (size_t)i * DMODEL * DINNER, DINNER, residual, DMODEL, DINNER);
    }

    final_kernel<<<BSZ, 256, 0, stream>>>(residual, mask, normf_w, out);
}

// Round 3
// 914.427 us; speedup vs baseline: 1.0201x; 1.0201x over previous
//
#include <hip/hip_runtime.h>
#include <hip/hip_bf16.h>

// ---- problem constants ----
#define BSZ 2
#define LSEQ 1024
#define DMODEL 768
#define NLAYER 4
#define DINNER 1536
#define DSTATE 16
#define DCONV 4
#define DTRANK 48
#define NCHUNK 64
#define CLEN 16
#define XDSTR 128
#define XZLD (2 * DINNER)

typedef __bf16 bf16x8_t __attribute__((ext_vector_type(8)));
typedef float f32x4_t __attribute__((ext_vector_type(4)));
typedef unsigned short u16x8_t __attribute__((ext_vector_type(8)));
typedef __hip_bfloat16 bf16;

__device__ inline float bfbits2f(unsigned short u) {
    unsigned int x = ((unsigned int)u) << 16;
    return __builtin_bit_cast(float, x);
}
__device__ inline unsigned short f2bfbits(float f) {
    return __builtin_bit_cast(unsigned short, (__bf16)f);
}

__device__ inline float block_reduce_sum(float v, float* sbuf) {
    __syncthreads();
    #pragma unroll
    for (int o = 32; o > 0; o >>= 1) v += __shfl_down(v, o, 64);
    int wid = threadIdx.x >> 6;
    int lane = threadIdx.x & 63;
    if (lane == 0) sbuf[wid] = v;
    __syncthreads();
    if (threadIdx.x == 0) sbuf[0] = (sbuf[0] + sbuf[1]) + (sbuf[2] + sbuf[3]);
    __syncthreads();
    return sbuf[0];
}

// ---------------- init: weight prep f32->bf16 + embedding + xdbl zero ----------------
#define PN1 (NLAYER * 3072 * 768)
#define PN2 (NLAYER * 768 * 1536)
#define PN3 (NLAYER * 128 * 1536)
#define PN4 (BSZ * LSEQ * DMODEL)
#define PN5 (2 * BSZ * LSEQ * XDSTR)
// total = 14,942,208 + 1,572,864 + 524,288 = 17,039,360 -> grid 66560
__global__ __launch_bounds__(256) void init_kernel(
    const int* __restrict__ seq, const float* __restrict__ emb,
    const float* __restrict__ in_w, const float* __restrict__ out_w,
    const float* __restrict__ xp_w,
    float* __restrict__ residual, bf16* __restrict__ in16,
    bf16* __restrict__ out16, bf16* __restrict__ xp16, float* __restrict__ xdbl2) {
    int idx = blockIdx.x * 256 + threadIdx.x;
    if (idx < PN1) { in16[idx] = __float2bfloat16(in_w[idx]); return; }
    idx -= PN1;
    if (idx < PN2) { out16[idx] = __float2bfloat16(out_w[idx]); return; }
    idx -= PN2;
    if (idx < PN3) {
        int l = idx / (128 * DINNER);
        int r = idx - l * (128 * DINNER);
        int e = r / DINNER;
        int k = r - e * DINNER;
        xp16[idx] = (e < 80) ? __float2bfloat16(xp_w[((size_t)l * 80 + e) * DINNER + k])
                             : __float2bfloat16(0.f);
        return;
    }
    idx -= PN3;
    if (idx < PN4) {
        int bl = idx / DMODEL;
        int dd = idx - bl * DMODEL;
        residual[idx] = emb[(size_t)seq[bl] * DMODEL + dd];
        return;
    }
    idx -= PN4;
    xdbl2[idx] = 0.f;   // idx < PN5 guaranteed by grid size
}

// ---------------- rmsnorm -> bf16 ----------------
__global__ __launch_bounds__(256) void rmsnorm_kernel(
    const float* __restrict__ res, const float* __restrict__ w, bf16* __restrict__ out) {
    __shared__ float sbuf[8];
    int row = blockIdx.x;
    const float* x = res + (size_t)row * DMODEL;
    float ss = 0.f;
    for (int i = threadIdx.x; i < DMODEL; i += 256) { float v = x[i]; ss += v * v; }
    ss = block_reduce_sum(ss, sbuf);
    float scale = rsqrtf(ss / (float)DMODEL + 1e-5f);
    for (int i = threadIdx.x; i < DMODEL; i += 256)
        out[(size_t)row * DMODEL + i] = __float2bfloat16(x[i] * scale * w[i]);
}

// ---------------- GEMM 128x64 tile, bf16 in -> bf16 out (in_proj) ----------------
__global__ __launch_bounds__(256) void gemm_128x64(
    const bf16* __restrict__ A, int lda, const bf16* __restrict__ Bw, int ldb,
    bf16* __restrict__ C16, int ldc, int K) {
    __shared__ bf16 As[128][72];
    __shared__ bf16 Bs[64][72];
    int tid = threadIdx.x;
    int wave = tid >> 6;
    int lane = tid & 63;
    int quad = lane >> 4;
    int l16 = lane & 15;
    int bm = blockIdx.x * 128;
    int bn = blockIdx.y * 64;
    int wm = wave * 32;
    int arow = tid >> 1, ak = (tid & 1) * 32;
    int brow = tid >> 2, bk = (tid & 3) * 16;

    f32x4_t acc[2][4];
    #pragma unroll
    for (int i = 0; i < 2; ++i)
        #pragma unroll
        for (int j = 0; j < 4; ++j) acc[i][j] = (f32x4_t){0.f, 0.f, 0.f, 0.f};

    for (int k0 = 0; k0 < K; k0 += 64) {
        const bf16* ag = A + (size_t)(bm + arow) * lda + k0 + ak;
        const bf16* bg = Bw + (size_t)(bn + brow) * ldb + k0 + bk;
        *(int4*)&As[arow][ak]      = *(const int4*)(ag);
        *(int4*)&As[arow][ak + 8]  = *(const int4*)(ag + 8);
        *(int4*)&As[arow][ak + 16] = *(const int4*)(ag + 16);
        *(int4*)&As[arow][ak + 24] = *(const int4*)(ag + 24);
        *(int4*)&Bs[brow][bk]      = *(const int4*)(bg);
        *(int4*)&Bs[brow][bk + 8]  = *(const int4*)(bg + 8);
        __syncthreads();
        #pragma unroll
        for (int kk = 0; kk < 64; kk += 32) {
            bf16x8_t af[2], bf[4];
            #pragma unroll
            for (int i = 0; i < 2; ++i)
                af[i] = *(const bf16x8_t*)(&As[wm + i * 16 + l16][kk + quad * 8]);
            #pragma unroll
            for (int j = 0; j < 4; ++j)
                bf[j] = *(const bf16x8_t*)(&Bs[j * 16 + l16][kk + quad * 8]);
            #pragma unroll
            for (int i = 0; i < 2; ++i)
                #pragma unroll
                for (int j = 0; j < 4; ++j)
                    acc[i][j] = __builtin_amdgcn_mfma_f32_16x16x32_bf16(af[i], bf[j], acc[i][j], 0, 0, 0);
        }
        __syncthreads();
    }

    int mbase = bm + wm + quad * 4;
    #pragma unroll
    for (int i = 0; i < 2; ++i)
        #pragma unroll
        for (int j = 0; j < 4; ++j) {
            int n = bn + j * 16 + l16;
            #pragma unroll
            for (int r = 0; r < 4; ++r)
                C16[(size_t)(mbase + i * 16 + r) * ldc + n] = __float2bfloat16(acc[i][j][r]);
        }
}

// ---------------- GEMM 64x64 tile, bf16 in, split-K, atomicAdd f32 out (out_proj) ----------------
__global__ __launch_bounds__(256) void gemm_64_atomic(
    const bf16* __restrict__ A, int lda, const bf16* __restrict__ Bw, int ldb,
    float* __restrict__ Cf, int ldc, int K) {
    __shared__ bf16 As[64][72];
    __shared__ bf16 Bs[64][72];
    int tid = threadIdx.x;
    int wave = tid >> 6;
    int lane = tid & 63;
    int quad = lane >> 4;
    int l16 = lane & 15;
    int bm = blockIdx.x * 64;
    int bn = blockIdx.y * 64;
    int lrow = tid >> 2;
    int lk = (tid & 3) * 16;
    int kpb = K / gridDim.z;
    int kbeg = blockIdx.z * kpb;
    int kend = kbeg + kpb;

    f32x4_t acc[4];
    #pragma unroll
    for (int i = 0; i < 4; ++i) acc[i] = (f32x4_t){0.f, 0.f, 0.f, 0.f};

    for (int k0 = kbeg; k0 < kend; k0 += 64) {
        const bf16* ag = A + (size_t)(bm + lrow) * lda + k0 + lk;
        const bf16* bg = Bw + (size_t)(bn + lrow) * ldb + k0 + lk;
        *(int4*)&As[lrow][lk]     = *(const int4*)(ag);
        *(int4*)&As[lrow][lk + 8] = *(const int4*)(ag + 8);
        *(int4*)&Bs[lrow][lk]     = *(const int4*)(bg);
        *(int4*)&Bs[lrow][lk + 8] = *(const int4*)(bg + 8);
        __syncthreads();
        #pragma unroll
        for (int kk = 0; kk < 64; kk += 32) {
            bf16x8_t af = *(const bf16x8_t*)(&As[wave * 16 + l16][kk + quad * 8]);
            #pragma unroll
            for (int i = 0; i < 4; ++i) {
                bf16x8_t bv = *(const bf16x8_t*)(&Bs[i * 16 + l16][kk + quad * 8]);
                acc[i] = __builtin_amdgcn_mfma_f32_16x16x32_bf16(af, bv, acc[i], 0, 0, 0);
            }
        }
        __syncthreads();
    }

    int m0 = bm + wave * 16 + quad * 4;
    #pragma unroll
    for (int i = 0; i < 4; ++i) {
        int n = bn + i * 16 + l16;
        #pragma unroll
        for (int r = 0; r < 4; ++r)
            atomicAdd(&Cf[(size_t)(m0 + r) * ldc + n], acc[i][r]);
    }
}

// ---------------- x_proj GEMM 64x64, conv+bias+silu fused into A staging ----------------
// A[row][d] = silu(cb[d] + sum_t xz16[row-3+t][d]*cw[d][t]);  split-K=8 atomic f32 out
#define XKPB 192
__global__ __launch_bounds__(256) void xproj_conv_gemm(
    const bf16* __restrict__ xz16, const float* __restrict__ cw, const float* __restrict__ cb,
    const bf16* __restrict__ Bw, float* __restrict__ Cf) {
    __shared__ bf16 As[64][72];
    __shared__ bf16 Bs[64][72];
    int tid = threadIdx.x;
    int wave = tid >> 6;
    int lane = tid & 63;
    int quad = lane >> 4;
    int l16 = lane & 15;
    int bm = blockIdx.x * 64;
    int bn = blockIdx.y * 64;
    int lrow = tid >> 2;
    int lk = (tid & 3) * 16;
    int kbeg = blockIdx.z * XKPB;
    int kend = kbeg + XKPB;
    int row = bm + lrow;
    int l = row & (LSEQ - 1);

    f32x4_t acc[4];
    #pragma unroll
    for (int i = 0; i < 4; ++i) acc[i] = (f32x4_t){0.f, 0.f, 0.f, 0.f};

    for (int k0 = kbeg; k0 < kend; k0 += 64) {
        int d0 = k0 + lk;
        // ---- A stage: conv4 + bias + silu from xz16 x-half ----
        u16x8_t xa[4][2];
        const u16x8_t Z8 = (u16x8_t){0, 0, 0, 0, 0, 0, 0, 0};
        #pragma unroll
        for (int t = 0; t < 4; ++t) {
            if (l >= 3 - t) {
                const u16x8_t* p = (const u16x8_t*)(xz16 + (size_t)(row - 3 + t) * XZLD + d0);
                xa[t][0] = p[0];
                xa[t][1] = p[1];
            } else { xa[t][0] = Z8; xa[t][1] = Z8; }
        }
        float cbv[16];
        #pragma unroll
        for (int q = 0; q < 4; ++q)
            *(float4*)&cbv[q * 4] = *(const float4*)(cb + d0 + q * 4);
        u16x8_t r0, r1;
        #pragma unroll
        for (int j = 0; j < 8; ++j) {
            float4 cwv = *(const float4*)(cw + (size_t)(d0 + j) * 4);
            float a = cbv[j]
                + bfbits2f(xa[0][0][j]) * cwv.x + bfbits2f(xa[1][0][j]) * cwv.y
                + bfbits2f(xa[2][0][j]) * cwv.z + bfbits2f(xa[3][0][j]) * cwv.w;
            a = a / (1.f + __expf(-a));
            r0[j] = f2bfbits(a);
        }
        #pragma unroll
        for (int j = 0; j < 8; ++j) {
            float4 cwv = *(const float4*)(cw + (size_t)(d0 + 8 + j) * 4);
            float a = cbv[8 + j]
                + bfbits2f(xa[0][1][j]) * cwv.x + bfbits2f(xa[1][1][j]) * cwv.y
                + bfbits2f(xa[2][1][j]) * cwv.z + bfbits2f(xa[3][1][j]) * cwv.w;
            a = a / (1.f + __expf(-a));
            r1[j] = f2bfbits(a);
        }
        *(u16x8_t*)&As[lrow][lk]     = r0;
        *(u16x8_t*)&As[lrow][lk + 8] = r1;
        // ---- B stage ----
        const bf16* bg = Bw + (size_t)(bn + lrow) * DINNER + d0;
        *(int4*)&Bs[lrow][lk]     = *(const int4*)(bg);
        *(int4*)&Bs[lrow][lk + 8] = *(const int4*)(bg + 8);
        __syncthreads();
        #pragma unroll
        for (int kk = 0; kk < 64; kk += 32) {
            bf16x8_t af = *(const bf16x8_t*)(&As[wave * 16 + l16][kk + quad * 8]);
            #pragma unroll
            for (int i = 0; i < 4; ++i) {
                bf16x8_t bv = *(const bf16x8_t*)(&Bs[i * 16 + l16][kk + quad * 8]);
                acc[i] = __builtin_amdgcn_mfma_f32_16x16x32_bf16(af, bv, acc[i], 0, 0, 0);
            }
        }
        __syncthreads();
    }

    int m0 = bm + wave * 16 + quad * 4;
    #pragma unroll
    for (int i = 0; i < 4; ++i) {
        int n = bn + i * 16 + l16;
        #pragma unroll
        for (int r = 0; r < 4; ++r)
            atomicAdd(&Cf[(size_t)(m0 + r) * XDSTR + n], acc[i][r]);
    }
}

// ---------------- delta from f32 xdbl row (wave-uniform) + per-thread dtw ----------------
__device__ inline float compute_delta(const float* __restrict__ xrow,
                                      const float* __restrict__ dtw, float dtbd) {
    float acc = dtbd;
    #pragma unroll
    for (int j = 0; j < DTRANK; j += 4) {
        float4 xv = *(const float4*)(xrow + j);
        acc += xv.x * dtw[j] + xv.y * dtw[j + 1] + xv.z * dtw[j + 2] + xv.w * dtw[j + 3];
    }
    return (acc > 20.f) ? acc : log1pf(__expf(acc));
}

// ================= chunked scan (dt + conv fused) =================
__global__ __launch_bounds__(256) void scan_phaseA(
    const bf16* __restrict__ xz16, const float* __restrict__ cw, const float* __restrict__ cb,
    const float* __restrict__ xdbl,
    const float* __restrict__ dt_w, const float* __restrict__ dt_b,
    const float* __restrict__ A_log,
    float* __restrict__ Psum, float* __restrict__ Ssum,
    float* __restrict__ xd_next) {
    int gtid = blockIdx.x * 256 + threadIdx.x;
    int d = gtid % DINNER;
    int c = (gtid / DINNER) % NCHUNK;
    int b = gtid / (DINNER * NCHUNK);
    float dtw[DTRANK];
    #pragma unroll
    for (int j = 0; j < DTRANK; j += 4)
        *(float4*)(dtw + j) = *(const float4*)(dt_w + (size_t)d * DTRANK + j);
    float dtbd = dt_b[d];
    float4 cwv = *(const float4*)(cw + (size_t)d * DCONV);
    float cbd = cb[d];
    float Av[DSTATE], P[DSTATE], S[DSTATE];
    #pragma unroll
    for (int s = 0; s < DSTATE; ++s) {
        Av[s] = -__expf(A_log[d * DSTATE + s]);
        P[s] = 1.f; S[s] = 0.f;
    }
    int t0 = c * CLEN;
    int rowb = b * LSEQ;
    float x3 = (t0 >= 3) ? __bfloat162float(xz16[(size_t)(rowb + t0 - 3) * XZLD + d]) : 0.f;
    float x2 = (t0 >= 2) ? __bfloat162float(xz16[(size_t)(rowb + t0 - 2) * XZLD + d]) : 0.f;
    float x1 = (t0 >= 1) ? __bfloat162float(xz16[(size_t)(rowb + t0 - 1) * XZLD + d]) : 0.f;
    for (int i = 0; i < CLEN; ++i) {
        int row = rowb + t0 + i;
        const float* xrow = xdbl + (size_t)row * XDSTR;
        float dl = compute_delta(xrow, dtw, dtbd);
        float x0 = __bfloat162float(xz16[(size_t)row * XZLD + d]);
        float ur = cbd + x3 * cwv.x + x2 * cwv.y + x1 * cwv.z + x0 * cwv.w;
        float u = ur / (1.f + __expf(-ur));
        x3 = x2; x2 = x1; x1 = x0;
        float bt = dl * u;
        const float4* Bp = (const float4*)(xrow + DTRANK);
        float4 B0 = Bp[0], B1 = Bp[1], B2 = Bp[2], B3 = Bp[3];
        float Bv[DSTATE] = {B0.x,B0.y,B0.z,B0.w, B1.x,B1.y,B1.z,B1.w,
                            B2.x,B2.y,B2.z,B2.w, B3.x,B3.y,B3.z,B3.w};
        #pragma unroll
        for (int s = 0; s < DSTATE; ++s) {
            float a = __expf(dl * Av[s]);
            P[s] *= a;
            S[s] = a * S[s] + bt * Bv[s];
        }
    }
    size_t base = ((size_t)(b * NCHUNK + c) * DSTATE) * DINNER + d;
    #pragma unroll
    for (int s = 0; s < DSTATE; ++s) {
        Psum[base + (size_t)s * DINNER] = P[s];
        Ssum[base + (size_t)s * DINNER] = S[s];
    }
    // zero next layer's xdbl buffer (its last reader finished 2+ kernels ago)
    for (int z = gtid; z < BSZ * LSEQ * XDSTR; z += BSZ * NCHUNK * DINNER)
        xd_next[z] = 0.f;
}

__global__ __launch_bounds__(256) void scan_phaseB(
    const float* __restrict__ Psum, const float* __restrict__ Ssum,
    float* __restrict__ Hin) {
    int gtid = blockIdx.x * 256 + threadIdx.x;
    int d = gtid % DINNER;
    int s = (gtid / DINNER) % DSTATE;
    int b = gtid / (DINNER * DSTATE);
    float h = 0.f;
    for (int c = 0; c < NCHUNK; ++c) {
        size_t idx = ((size_t)(b * NCHUNK + c) * DSTATE + s) * DINNER + d;
        Hin[idx] = h;
        h = Psum[idx] * h + Ssum[idx];
    }
}

__global__ __launch_bounds__(256) void scan_phaseC(
    const bf16* __restrict__ xz16, const float* __restrict__ cw, const float* __restrict__ cb,
    const float* __restrict__ xdbl,
    const float* __restrict__ dt_w, const float* __restrict__ dt_b,
    const float* __restrict__ A_log, const float* __restrict__ D_skip,
    const float* __restrict__ Hin, bf16* __restrict__ y16) {
    int gtid = blockIdx.x * 256 + threadIdx.x;
    int d = gtid % DINNER;
    int c = (gtid / DINNER) % NCHUNK;
    int b = gtid / (DINNER * NCHUNK);
    float dtw[DTRANK];
    #pragma unroll
    for (int j = 0; j < DTRANK; j += 4)
        *(float4*)(dtw + j) = *(const float4*)(dt_w + (size_t)d * DTRANK + j);
    float dtbd = dt_b[d];
    float4 cwv = *(const float4*)(cw + (size_t)d * DCONV);
    float cbd = cb[d];
    float Av[DSTATE], h[DSTATE];
    size_t base = ((size_t)(b * NCHUNK + c) * DSTATE) * DINNER + d;
    #pragma unroll
    for (int s = 0; s < DSTATE; ++s) {
        Av[s] = -__expf(A_log[d * DSTATE + s]);
        h[s] = Hin[base + (size_t)s * DINNER];
    }
    float Dsk = D_skip[d];
    int t0 = c * CLEN;
    int rowb = b * LSEQ;
    float x3 = (t0 >= 3) ? __bfloat162float(xz16[(size_t)(rowb + t0 - 3) * XZLD + d]) : 0.f;
    float x2 = (t0 >= 2) ? __bfloat162float(xz16[(size_t)(rowb + t0 - 2) * XZLD + d]) : 0.f;
    float x1 = (t0 >= 1) ? __bfloat162float(xz16[(size_t)(rowb + t0 - 1) * XZLD + d]) : 0.f;
    for (int i = 0; i < CLEN; ++i) {
        int row = rowb + t0 + i;
        const float* xrow = xdbl + (size_t)row * XDSTR;
        float dl = compute_delta(xrow, dtw, dtbd);
        float x0 = __bfloat162float(xz16[(size_t)row * XZLD + d]);
        float ur = cbd + x3 * cwv.x + x2 * cwv.y + x1 * cwv.z + x0 * cwv.w;
        float u = ur / (1.f + __expf(-ur));
        x3 = x2; x2 = x1; x1 = x0;
        float bt = dl * u;
        const float4* Bp = (const float4*)(xrow + DTRANK);
        float4 B0 = Bp[0], B1 = Bp[1], B2 = Bp[2], B3 = Bp[3];
        const float4* Cp = (const float4*)(xrow + DTRANK + DSTATE);
        float4 C0 = Cp[0], C1 = Cp[1], C2 = Cp[2], C3 = Cp[3];
        float Bv[DSTATE] = {B0.x,B0.y,B0.z,B0.w, B1.x,B1.y,B1.z,B1.w,
                            B2.x,B2.y,B2.z,B2.w, B3.x,B3.y,B3.z,B3.w};
        float Cv[DSTATE] = {C0.x,C0.y,C0.z,C0.w, C1.x,C1.y,C1.z,C1.w,
                            C2.x,C2.y,C2.z,C2.w, C3.x,C3.y,C3.z,C3.w};
        float acc = 0.f;
        #pragma unroll
        for (int s = 0; s < DSTATE; ++s) {
            float a = __expf(dl * Av[s]);
            h[s] = a * h[s] + bt * Bv[s];
            acc += h[s] * Cv[s];
        }
        float zv = __bfloat162float(xz16[(size_t)row * XZLD + DINNER + d]);
        float sz = zv / (1.f + __expf(-zv));
        y16[(size_t)row * DINNER + d] = __float2bfloat16((acc + u * Dsk) * sz);
    }
}

// ---------------- final: last-token rmsnorm ----------------
__global__ __launch_bounds__(256) void final_kernel(
    const float* __restrict__ res, const int* __restrict__ mask,
    const float* __restrict__ w, float* __restrict__ out) {
    __shared__ float sbuf[8];
    int b = blockIdx.x;
    float cnt = 0.f;
    for (int i = threadIdx.x; i < LSEQ; i += 256) cnt += (float)mask[b * LSEQ + i];
    cnt = block_reduce_sum(cnt, sbuf);
    int last = (int)cnt - 1;
    const float* x = res + ((size_t)b * LSEQ + last) * DMODEL;
    float ss = 0.f;
    for (int i = threadIdx.x; i < DMODEL; i += 256) { float v = x[i]; ss += v * v; }
    ss = block_reduce_sum(ss, sbuf);
    float scale = rsqrtf(ss / (float)DMODEL + 1e-5f);
    for (int i = threadIdx.x; i < DMODEL; i += 256)
        out[b * DMODEL + i] = x[i] * scale * w[i];
}

extern "C" void kernel_launch(void* const* d_in, const int* in_sizes, int n_in,
                              void* d_out, int out_size, void* d_ws, size_t ws_size,
                              hipStream_t stream) {
    const int*   seq      = (const int*)d_in[0];
    const int*   mask     = (const int*)d_in[1];
    const float* emb      = (const float*)d_in[2];
    const float* norm_w   = (const float*)d_in[3];
    const float* in_w     = (const float*)d_in[4];
    const float* conv_w   = (const float*)d_in[5];
    const float* conv_b   = (const float*)d_in[6];
    const float* xp_w     = (const float*)d_in[7];
    const float* dt_w     = (const float*)d_in[8];
    const float* dt_b     = (const float*)d_in[9];
    const float* A_log    = (const float*)d_in[10];
    const float* D_skip   = (const float*)d_in[11];
    const float* out_w    = (const float*)d_in[12];
    const float* normf_w  = (const float*)d_in[13];
    float* out = (float*)d_out;

    char* ws = (char*)d_ws;
    float* residual = (float*)(ws);                      //  6,291,456
    bf16*  hn16     = (bf16*)(ws + 6291456);             //  3,145,728
    bf16*  xz16     = (bf16*)(ws + 9437184);             // 12,582,912
    float* xdbl     = (float*)(ws + 22020096);           //  2,097,152 (2 buffers)
    bf16*  ybuf16   = (bf16*)(ws + 24117248);            //  6,291,456
    float* Psum     = (float*)(ws + 30408704);           // 12,582,912
    float* Ssum     = (float*)(ws + 42991616);           // 12,582,912
    float* Hin      = (float*)(ws + 55574528);           // 12,582,912
    bf16*  in16     = (bf16*)(ws + 68157440);            // 18,874,368
    bf16*  out16    = (bf16*)(ws + 87031808);            //  9,437,184
    bf16*  xp16     = (bf16*)(ws + 96468992);            //  1,572,864
                                                         // total 98,041,856 bytes

    init_kernel<<<66560, 256, 0, stream>>>(seq, emb, in_w, out_w, xp_w,
                                           residual, in16, out16, xp16, xdbl);

    for (int i = 0; i < NLAYER; ++i) {
        float* xd_cur = xdbl + (size_t)(i & 1) * (BSZ * LSEQ * XDSTR);
        float* xd_nxt = xdbl + (size_t)((i + 1) & 1) * (BSZ * LSEQ * XDSTR);
        const float* cw = conv_w + (size_t)i * DINNER * DCONV;
        const float* cb = conv_b + (size_t)i * DINNER;
        const float* dw = dt_w + (size_t)i * DINNER * DTRANK;
        const float* db = dt_b + (size_t)i * DINNER;
        const float* al = A_log + (size_t)i * DINNER * DSTATE;

        rmsnorm_kernel<<<BSZ * LSEQ, 256, 0, stream>>>(residual, norm_w + (size_t)i * DMODEL, hn16);
        // in_proj: xz16(2048x3072) = hn16 @ in16[i]^T  (grid 768, 3 blocks/CU balanced)
        gemm_128x64<<<dim3(16, 48), 256, 0, stream>>>(
            hn16, DMODEL, in16 + (size_t)i * 3072 * DMODEL, DMODEL, xz16, XZLD, DMODEL);
        // x_proj (conv+silu fused into A staging): xdbl(2048x128) f32, split-K=8 (grid 512)
        xproj_conv_gemm<<<dim3(32, 2, 8), 256, 0, stream>>>(
            xz16, cw, cb, xp16 + (size_t)i * 128 * DINNER, xd_cur);
        scan_phaseA<<<768, 256, 0, stream>>>(
            xz16, cw, cb, xd_cur, dw, db, al, Psum, Ssum, xd_nxt);
        scan_phaseB<<<192, 256, 0, stream>>>(Psum, Ssum, Hin);
        scan_phaseC<<<768, 256, 0, stream>>>(
            xz16, cw, cb, xd_cur, dw, db, al, D_skip + (size_t)i * DINNER, Hin, ybuf16);
        // out_proj: residual += ybuf16 @ out16[i]^T, split-K=2 (grid 768, 3 blocks/CU)
        gemm_64_atomic<<<dim3(32, 12, 2), 256, 0, stream>>>(
            ybuf16, DINNER, out16 + (size_t)i * DMODEL * DINNER, DINNER, residual, DMODEL, DINNER);
    }

    final_kernel<<<BSZ, 256, 0, stream>>>(residual, mask, normf_w, out);
}

// Round 4
// 865.068 us; speedup vs baseline: 1.0783x; 1.0571x over previous
//
#include <hip/hip_runtime.h>
#include <hip/hip_bf16.h>

// ---- problem constants ----
#define BSZ 2
#define LSEQ 1024
#define DMODEL 768
#define NLAYER 4
#define DINNER 1536
#define DSTATE 16
#define DCONV 4
#define DTRANK 48
#define NCHUNK 64
#define CLEN 16
#define XDSTR 128
#define XZLD (2 * DINNER)

typedef __bf16 bf16x8_t __attribute__((ext_vector_type(8)));
typedef float f32x4_t __attribute__((ext_vector_type(4)));
typedef unsigned short u16x8_t __attribute__((ext_vector_type(8)));
typedef __hip_bfloat16 bf16;

__device__ inline float bfbits2f(unsigned short u) {
    unsigned int x = ((unsigned int)u) << 16;
    return __builtin_bit_cast(float, x);
}
__device__ inline unsigned short f2bfbits(float f) {
    return __builtin_bit_cast(unsigned short, (__bf16)f);
}

// async global->LDS, 16B per lane. dest = wave-uniform base + lane*16 (HW).
__device__ __forceinline__ void gload16(const bf16* g, bf16* l) {
    __builtin_amdgcn_global_load_lds(
        (const __attribute__((address_space(1))) unsigned int*)g,
        (__attribute__((address_space(3))) unsigned int*)l,
        16, 0, 0);
}

__device__ inline float block_reduce_sum(float v, float* sbuf) {
    __syncthreads();
    #pragma unroll
    for (int o = 32; o > 0; o >>= 1) v += __shfl_down(v, o, 64);
    int wid = threadIdx.x >> 6;
    int lane = threadIdx.x & 63;
    if (lane == 0) sbuf[wid] = v;
    __syncthreads();
    if (threadIdx.x == 0) sbuf[0] = (sbuf[0] + sbuf[1]) + (sbuf[2] + sbuf[3]);
    __syncthreads();
    return sbuf[0];
}

// ---------------- init: weight prep f32->bf16 + embedding + xdbl zero ----------------
#define PN1 (NLAYER * 3072 * 768)
#define PN2 (NLAYER * 768 * 1536)
#define PN3 (NLAYER * 128 * 1536)
#define PN4 (BSZ * LSEQ * DMODEL)
#define PN5 (2 * BSZ * LSEQ * XDSTR)
// total = 17,039,360 -> grid 66560
__global__ __launch_bounds__(256) void init_kernel(
    const int* __restrict__ seq, const float* __restrict__ emb,
    const float* __restrict__ in_w, const float* __restrict__ out_w,
    const float* __restrict__ xp_w,
    float* __restrict__ residual, bf16* __restrict__ in16,
    bf16* __restrict__ out16, bf16* __restrict__ xp16, float* __restrict__ xdbl2) {
    int idx = blockIdx.x * 256 + threadIdx.x;
    if (idx < PN1) { in16[idx] = __float2bfloat16(in_w[idx]); return; }
    idx -= PN1;
    if (idx < PN2) { out16[idx] = __float2bfloat16(out_w[idx]); return; }
    idx -= PN2;
    if (idx < PN3) {
        int l = idx / (128 * DINNER);
        int r = idx - l * (128 * DINNER);
        int e = r / DINNER;
        int k = r - e * DINNER;
        xp16[idx] = (e < 80) ? __float2bfloat16(xp_w[((size_t)l * 80 + e) * DINNER + k])
                             : __float2bfloat16(0.f);
        return;
    }
    idx -= PN3;
    if (idx < PN4) {
        int bl = idx / DMODEL;
        int dd = idx - bl * DMODEL;
        residual[idx] = emb[(size_t)seq[bl] * DMODEL + dd];
        return;
    }
    idx -= PN4;
    xdbl2[idx] = 0.f;
}

// ---------------- rmsnorm -> bf16 ----------------
__global__ __launch_bounds__(256) void rmsnorm_kernel(
    const float* __restrict__ res, const float* __restrict__ w, bf16* __restrict__ out) {
    __shared__ float sbuf[8];
    int row = blockIdx.x;
    const float* x = res + (size_t)row * DMODEL;
    float ss = 0.f;
    for (int i = threadIdx.x; i < DMODEL; i += 256) { float v = x[i]; ss += v * v; }
    ss = block_reduce_sum(ss, sbuf);
    float scale = rsqrtf(ss / (float)DMODEL + 1e-5f);
    for (int i = threadIdx.x; i < DMODEL; i += 256)
        out[(size_t)row * DMODEL + i] = __float2bfloat16(x[i] * scale * w[i]);
}

// ---------------- GEMM 128x64 tile, async gload_lds + XOR swizzle (in_proj) ----------------
// LDS linear [rows][64], source pre-swizzled chunk c^=(row&7), read applies same XOR.
__global__ __launch_bounds__(256) void gemm_128x64_g(
    const bf16* __restrict__ A, int lda, const bf16* __restrict__ Bw, int ldb,
    bf16* __restrict__ C16, int ldc, int K) {
    __shared__ bf16 As[128][64];
    __shared__ bf16 Bs[64][64];
    int tid = threadIdx.x;
    int wave = tid >> 6;
    int lane = tid & 63;
    int quad = lane >> 4;
    int l16 = lane & 15;
    int bm = blockIdx.x * 128;
    int bn = blockIdx.y * 64;
    int wm = wave * 32;
    int lr = lane >> 3;                 // row within 8-row chunk
    int lc = (lane & 7) ^ lr;           // pre-swizzled 16B col-chunk
    int sx = (l16 & 7) << 3;            // read-side elem XOR

    f32x4_t acc[2][4];
    #pragma unroll
    for (int i = 0; i < 2; ++i)
        #pragma unroll
        for (int j = 0; j < 4; ++j) acc[i][j] = (f32x4_t){0.f, 0.f, 0.f, 0.f};

    for (int k0 = 0; k0 < K; k0 += 64) {
        // 24 chunks of 1KB: 0-15 -> As (128x64), 16-23 -> Bs (64x64); 6 per wave
        #pragma unroll
        for (int i = 0; i < 6; ++i) {
            int ch = wave * 6 + i;
            if (ch < 16) {
                int r = ch * 8 + lr;
                gload16(A + (size_t)(bm + r) * lda + k0 + lc * 8, &As[ch * 8][0]);
            } else {
                int c2 = ch - 16;
                int r = c2 * 8 + lr;
                gload16(Bw + (size_t)(bn + r) * ldb + k0 + lc * 8, &Bs[c2 * 8][0]);
            }
        }
        __syncthreads();   // drains vmcnt(0): gload_lds complete
        #pragma unroll
        for (int kk = 0; kk < 64; kk += 32) {
            bf16x8_t af[2], bf[4];
            #pragma unroll
            for (int i = 0; i < 2; ++i)
                af[i] = *(const bf16x8_t*)(&As[wm + i * 16 + l16][(kk + quad * 8) ^ sx]);
            #pragma unroll
            for (int j = 0; j < 4; ++j)
                bf[j] = *(const bf16x8_t*)(&Bs[j * 16 + l16][(kk + quad * 8) ^ sx]);
            #pragma unroll
            for (int i = 0; i < 2; ++i)
                #pragma unroll
                for (int j = 0; j < 4; ++j)
                    acc[i][j] = __builtin_amdgcn_mfma_f32_16x16x32_bf16(af[i], bf[j], acc[i][j], 0, 0, 0);
        }
        __syncthreads();
    }

    int mbase = bm + wm + quad * 4;
    #pragma unroll
    for (int i = 0; i < 2; ++i)
        #pragma unroll
        for (int j = 0; j < 4; ++j) {
            int n = bn + j * 16 + l16;
            #pragma unroll
            for (int r = 0; r < 4; ++r)
                C16[(size_t)(mbase + i * 16 + r) * ldc + n] = __float2bfloat16(acc[i][j][r]);
        }
}

// ---------------- GEMM 64x64 tile, async staging, split-K atomicAdd f32 (out_proj) ----------------
__global__ __launch_bounds__(256) void gemm_64_atomic_g(
    const bf16* __restrict__ A, int lda, const bf16* __restrict__ Bw, int ldb,
    float* __restrict__ Cf, int ldc, int K) {
    __shared__ bf16 As[64][64];
    __shared__ bf16 Bs[64][64];
    int tid = threadIdx.x;
    int wave = tid >> 6;
    int lane = tid & 63;
    int quad = lane >> 4;
    int l16 = lane & 15;
    int bm = blockIdx.x * 64;
    int bn = blockIdx.y * 64;
    int lr = lane >> 3;
    int lc = (lane & 7) ^ lr;
    int sx = (l16 & 7) << 3;
    int kpb = K / gridDim.z;
    int kbeg = blockIdx.z * kpb;
    int kend = kbeg + kpb;

    f32x4_t acc[4];
    #pragma unroll
    for (int i = 0; i < 4; ++i) acc[i] = (f32x4_t){0.f, 0.f, 0.f, 0.f};

    for (int k0 = kbeg; k0 < kend; k0 += 64) {
        // 16 chunks: 0-7 -> As, 8-15 -> Bs; 4 per wave
        #pragma unroll
        for (int i = 0; i < 4; ++i) {
            int ch = wave * 4 + i;
            if (ch < 8) {
                int r = ch * 8 + lr;
                gload16(A + (size_t)(bm + r) * lda + k0 + lc * 8, &As[ch * 8][0]);
            } else {
                int c2 = ch - 8;
                int r = c2 * 8 + lr;
                gload16(Bw + (size_t)(bn + r) * ldb + k0 + lc * 8, &Bs[c2 * 8][0]);
            }
        }
        __syncthreads();
        #pragma unroll
        for (int kk = 0; kk < 64; kk += 32) {
            bf16x8_t af = *(const bf16x8_t*)(&As[wave * 16 + l16][(kk + quad * 8) ^ sx]);
            #pragma unroll
            for (int i = 0; i < 4; ++i) {
                bf16x8_t bv = *(const bf16x8_t*)(&Bs[i * 16 + l16][(kk + quad * 8) ^ sx]);
                acc[i] = __builtin_amdgcn_mfma_f32_16x16x32_bf16(af, bv, acc[i], 0, 0, 0);
            }
        }
        __syncthreads();
    }

    int m0 = bm + wave * 16 + quad * 4;
    #pragma unroll
    for (int i = 0; i < 4; ++i) {
        int n = bn + i * 16 + l16;
        #pragma unroll
        for (int r = 0; r < 4; ++r)
            atomicAdd(&Cf[(size_t)(m0 + r) * ldc + n], acc[i][r]);
    }
}

// ---------------- x_proj GEMM 64x64, conv+silu fused A (padded LDS), async B ----------------
#define XKPB 192
__global__ __launch_bounds__(256) void xproj_conv_gemm(
    const bf16* __restrict__ xz16, const float* __restrict__ cw, const float* __restrict__ cb,
    const bf16* __restrict__ Bw, float* __restrict__ Cf) {
    __shared__ bf16 As[64][72];   // computed tile: padded, ds_write
    __shared__ bf16 Bs[64][64];   // weight tile: async linear + swizzle
    int tid = threadIdx.x;
    int wave = tid >> 6;
    int lane = tid & 63;
    int quad = lane >> 4;
    int l16 = lane & 15;
    int bm = blockIdx.x * 64;
    int bn = blockIdx.y * 64;
    int lrow = tid >> 2;
    int lk = (tid & 3) * 16;
    int lr = lane >> 3;
    int lc = (lane & 7) ^ lr;
    int sx = (l16 & 7) << 3;
    int kbeg = blockIdx.z * XKPB;
    int kend = kbeg + XKPB;
    int row = bm + lrow;
    int l = row & (LSEQ - 1);

    f32x4_t acc[4];
    #pragma unroll
    for (int i = 0; i < 4; ++i) acc[i] = (f32x4_t){0.f, 0.f, 0.f, 0.f};

    for (int k0 = kbeg; k0 < kend; k0 += 64) {
        int d0 = k0 + lk;
        // ---- B stage first (async; latency hides under A-compute) ----
        #pragma unroll
        for (int i = 0; i < 2; ++i) {
            int ch = wave * 2 + i;       // 8 chunks over 4 waves
            int r = ch * 8 + lr;
            gload16(Bw + (size_t)(bn + r) * DINNER + k0 + lc * 8, &Bs[ch * 8][0]);
        }
        // ---- A stage: conv4 + bias + silu from xz16 x-half ----
        u16x8_t xa[4][2];
        const u16x8_t Z8 = (u16x8_t){0, 0, 0, 0, 0, 0, 0, 0};
        #pragma unroll
        for (int t = 0; t < 4; ++t) {
            if (l >= 3 - t) {
                const u16x8_t* p = (const u16x8_t*)(xz16 + (size_t)(row - 3 + t) * XZLD + d0);
                xa[t][0] = p[0];
                xa[t][1] = p[1];
            } else { xa[t][0] = Z8; xa[t][1] = Z8; }
        }
        float cbv[16];
        #pragma unroll
        for (int q = 0; q < 4; ++q)
            *(float4*)&cbv[q * 4] = *(const float4*)(cb + d0 + q * 4);
        u16x8_t r0, r1;
        #pragma unroll
        for (int j = 0; j < 8; ++j) {
            float4 cwv = *(const float4*)(cw + (size_t)(d0 + j) * 4);
            float a = cbv[j]
                + bfbits2f(xa[0][0][j]) * cwv.x + bfbits2f(xa[1][0][j]) * cwv.y
                + bfbits2f(xa[2][0][j]) * cwv.z + bfbits2f(xa[3][0][j]) * cwv.w;
            a = a / (1.f + __expf(-a));
            r0[j] = f2bfbits(a);
        }
        #pragma unroll
        for (int j = 0; j < 8; ++j) {
            float4 cwv = *(const float4*)(cw + (size_t)(d0 + 8 + j) * 4);
            float a = cbv[8 + j]
                + bfbits2f(xa[0][1][j]) * cwv.x + bfbits2f(xa[1][1][j]) * cwv.y
                + bfbits2f(xa[2][1][j]) * cwv.z + bfbits2f(xa[3][1][j]) * cwv.w;
            a = a / (1.f + __expf(-a));
            r1[j] = f2bfbits(a);
        }
        *(u16x8_t*)&As[lrow][lk]     = r0;
        *(u16x8_t*)&As[lrow][lk + 8] = r1;
        __syncthreads();
        #pragma unroll
        for (int kk = 0; kk < 64; kk += 32) {
            bf16x8_t af = *(const bf16x8_t*)(&As[wave * 16 + l16][kk + quad * 8]);
            #pragma unroll
            for (int i = 0; i < 4; ++i) {
                bf16x8_t bv = *(const bf16x8_t*)(&Bs[i * 16 + l16][(kk + quad * 8) ^ sx]);
                acc[i] = __builtin_amdgcn_mfma_f32_16x16x32_bf16(af, bv, acc[i], 0, 0, 0);
            }
        }
        __syncthreads();
    }

    int m0 = bm + wave * 16 + quad * 4;
    #pragma unroll
    for (int i = 0; i < 4; ++i) {
        int n = bn + i * 16 + l16;
        #pragma unroll
        for (int r = 0; r < 4; ++r)
            atomicAdd(&Cf[(size_t)(m0 + r) * XDSTR + n], acc[i][r]);
    }
}

// ---------------- delta from f32 xdbl row (wave-uniform) + per-thread dtw ----------------
__device__ inline float compute_delta(const float* __restrict__ xrow,
                                      const float* __restrict__ dtw, float dtbd) {
    float acc = dtbd;
    #pragma unroll
    for (int j = 0; j < DTRANK; j += 4) {
        float4 xv = *(const float4*)(xrow + j);
        acc += xv.x * dtw[j] + xv.y * dtw[j + 1] + xv.z * dtw[j + 2] + xv.w * dtw[j + 3];
    }
    return (acc > 20.f) ? acc : log1pf(__expf(acc));
}

// ================= chunked scan (dt + conv fused) =================
__global__ __launch_bounds__(256) void scan_phaseA(
    const bf16* __restrict__ xz16, const float* __restrict__ cw, const float* __restrict__ cb,
    const float* __restrict__ xdbl,
    const float* __restrict__ dt_w, const float* __restrict__ dt_b,
    const float* __restrict__ A_log,
    float* __restrict__ Psum, float* __restrict__ Ssum,
    float* __restrict__ xd_next) {
    int gtid = blockIdx.x * 256 + threadIdx.x;
    int d = gtid % DINNER;
    int c = (gtid / DINNER) % NCHUNK;
    int b = gtid / (DINNER * NCHUNK);
    float dtw[DTRANK];
    #pragma unroll
    for (int j = 0; j < DTRANK; j += 4)
        *(float4*)(dtw + j) = *(const float4*)(dt_w + (size_t)d * DTRANK + j);
    float dtbd = dt_b[d];
    float4 cwv = *(const float4*)(cw + (size_t)d * DCONV);
    float cbd = cb[d];
    float Av[DSTATE], P[DSTATE], S[DSTATE];
    #pragma unroll
    for (int s = 0; s < DSTATE; ++s) {
        Av[s] = -__expf(A_log[d * DSTATE + s]);
        P[s] = 1.f; S[s] = 0.f;
    }
    int t0 = c * CLEN;
    int rowb = b * LSEQ;
    float x3 = (t0 >= 3) ? __bfloat162float(xz16[(size_t)(rowb + t0 - 3) * XZLD + d]) : 0.f;
    float x2 = (t0 >= 2) ? __bfloat162float(xz16[(size_t)(rowb + t0 - 2) * XZLD + d]) : 0.f;
    float x1 = (t0 >= 1) ? __bfloat162float(xz16[(size_t)(rowb + t0 - 1) * XZLD + d]) : 0.f;
    for (int i = 0; i < CLEN; ++i) {
        int row = rowb + t0 + i;
        const float* xrow = xdbl + (size_t)row * XDSTR;
        float dl = compute_delta(xrow, dtw, dtbd);
        float x0 = __bfloat162float(xz16[(size_t)row * XZLD + d]);
        float ur = cbd + x3 * cwv.x + x2 * cwv.y + x1 * cwv.z + x0 * cwv.w;
        float u = ur / (1.f + __expf(-ur));
        x3 = x2; x2 = x1; x1 = x0;
        float bt = dl * u;
        const float4* Bp = (const float4*)(xrow + DTRANK);
        float4 B0 = Bp[0], B1 = Bp[1], B2 = Bp[2], B3 = Bp[3];
        float Bv[DSTATE] = {B0.x,B0.y,B0.z,B0.w, B1.x,B1.y,B1.z,B1.w,
                            B2.x,B2.y,B2.z,B2.w, B3.x,B3.y,B3.z,B3.w};
        #pragma unroll
        for (int s = 0; s < DSTATE; ++s) {
            float a = __expf(dl * Av[s]);
            P[s] *= a;
            S[s] = a * S[s] + bt * Bv[s];
        }
    }
    size_t base = ((size_t)(b * NCHUNK + c) * DSTATE) * DINNER + d;
    #pragma unroll
    for (int s = 0; s < DSTATE; ++s) {
        Psum[base + (size_t)s * DINNER] = P[s];
        Ssum[base + (size_t)s * DINNER] = S[s];
    }
    // zero next layer's xdbl buffer (its last reader finished 2+ kernels ago)
    for (int z = gtid; z < BSZ * LSEQ * XDSTR; z += BSZ * NCHUNK * DINNER)
        xd_next[z] = 0.f;
}

__global__ __launch_bounds__(256) void scan_phaseB(
    const float* __restrict__ Psum, const float* __restrict__ Ssum,
    float* __restrict__ Hin) {
    int gtid = blockIdx.x * 256 + threadIdx.x;
    int d = gtid % DINNER;
    int s = (gtid / DINNER) % DSTATE;
    int b = gtid / (DINNER * DSTATE);
    float h = 0.f;
    for (int c = 0; c < NCHUNK; ++c) {
        size_t idx = ((size_t)(b * NCHUNK + c) * DSTATE + s) * DINNER + d;
        Hin[idx] = h;
        h = Psum[idx] * h + Ssum[idx];
    }
}

__global__ __launch_bounds__(256) void scan_phaseC(
    const bf16* __restrict__ xz16, const float* __restrict__ cw, const float* __restrict__ cb,
    const float* __restrict__ xdbl,
    const float* __restrict__ dt_w, const float* __restrict__ dt_b,
    const float* __restrict__ A_log, const float* __restrict__ D_skip,
    const float* __restrict__ Hin, bf16* __restrict__ y16) {
    int gtid = blockIdx.x * 256 + threadIdx.x;
    int d = gtid % DINNER;
    int c = (gtid / DINNER) % NCHUNK;
    int b = gtid / (DINNER * NCHUNK);
    float dtw[DTRANK];
    #pragma unroll
    for (int j = 0; j < DTRANK; j += 4)
        *(float4*)(dtw + j) = *(const float4*)(dt_w + (size_t)d * DTRANK + j);
    float dtbd = dt_b[d];
    float4 cwv = *(const float4*)(cw + (size_t)d * DCONV);
    float cbd = cb[d];
    float Av[DSTATE], h[DSTATE];
    size_t base = ((size_t)(b * NCHUNK + c) * DSTATE) * DINNER + d;
    #pragma unroll
    for (int s = 0; s < DSTATE; ++s) {
        Av[s] = -__expf(A_log[d * DSTATE + s]);
        h[s] = Hin[base + (size_t)s * DINNER];
    }
    float Dsk = D_skip[d];
    int t0 = c * CLEN;
    int rowb = b * LSEQ;
    float x3 = (t0 >= 3) ? __bfloat162float(xz16[(size_t)(rowb + t0 - 3) * XZLD + d]) : 0.f;
    float x2 = (t0 >= 2) ? __bfloat162float(xz16[(size_t)(rowb + t0 - 2) * XZLD + d]) : 0.f;
    float x1 = (t0 >= 1) ? __bfloat162float(xz16[(size_t)(rowb + t0 - 1) * XZLD + d]) : 0.f;
    for (int i = 0; i < CLEN; ++i) {
        int row = rowb + t0 + i;
        const float* xrow = xdbl + (size_t)row * XDSTR;
        float dl = compute_delta(xrow, dtw, dtbd);
        float x0 = __bfloat162float(xz16[(size_t)row * XZLD + d]);
        float ur = cbd + x3 * cwv.x + x2 * cwv.y + x1 * cwv.z + x0 * cwv.w;
        float u = ur / (1.f + __expf(-ur));
        x3 = x2; x2 = x1; x1 = x0;
        float bt = dl * u;
        const float4* Bp = (const float4*)(xrow + DTRANK);
        float4 B0 = Bp[0], B1 = Bp[1], B2 = Bp[2], B3 = Bp[3];
        const float4* Cp = (const float4*)(xrow + DTRANK + DSTATE);
        float4 C0 = Cp[0], C1 = Cp[1], C2 = Cp[2], C3 = Cp[3];
        float Bv[DSTATE] = {B0.x,B0.y,B0.z,B0.w, B1.x,B1.y,B1.z,B1.w,
                            B2.x,B2.y,B2.z,B2.w, B3.x,B3.y,B3.z,B3.w};
        float Cv[DSTATE] = {C0.x,C0.y,C0.z,C0.w, C1.x,C1.y,C1.z,C1.w,
                            C2.x,C2.y,C2.z,C2.w, C3.x,C3.y,C3.z,C3.w};
        float acc = 0.f;
        #pragma unroll
        for (int s = 0; s < DSTATE; ++s) {
            float a = __expf(dl * Av[s]);
            h[s] = a * h[s] + bt * Bv[s];
            acc += h[s] * Cv[s];
        }
        float zv = __bfloat162float(xz16[(size_t)row * XZLD + DINNER + d]);
        float sz = zv / (1.f + __expf(-zv));
        y16[(size_t)row * DINNER + d] = __float2bfloat16((acc + u * Dsk) * sz);
    }
}

// ---------------- final: last-token rmsnorm ----------------
__global__ __launch_bounds__(256) void final_kernel(
    const float* __restrict__ res, const int* __restrict__ mask,
    const float* __restrict__ w, float* __restrict__ out) {
    __shared__ float sbuf[8];
    int b = blockIdx.x;
    float cnt = 0.f;
    for (int i = threadIdx.x; i < LSEQ; i += 256) cnt += (float)mask[b * LSEQ + i];
    cnt = block_reduce_sum(cnt, sbuf);
    int last = (int)cnt - 1;
    const float* x = res + ((size_t)b * LSEQ + last) * DMODEL;
    float ss = 0.f;
    for (int i = threadIdx.x; i < DMODEL; i += 256) { float v = x[i]; ss += v * v; }
    ss = block_reduce_sum(ss, sbuf);
    float scale = rsqrtf(ss / (float)DMODEL + 1e-5f);
    for (int i = threadIdx.x; i < DMODEL; i += 256)
        out[b * DMODEL + i] = x[i] * scale * w[i];
}

extern "C" void kernel_launch(void* const* d_in, const int* in_sizes, int n_in,
                              void* d_out, int out_size, void* d_ws, size_t ws_size,
                              hipStream_t stream) {
    const int*   seq      = (const int*)d_in[0];
    const int*   mask     = (const int*)d_in[1];
    const float* emb      = (const float*)d_in[2];
    const float* norm_w   = (const float*)d_in[3];
    const float* in_w     = (const float*)d_in[4];
    const float* conv_w   = (const float*)d_in[5];
    const float* conv_b   = (const float*)d_in[6];
    const float* xp_w     = (const float*)d_in[7];
    const float* dt_w     = (const float*)d_in[8];
    const float* dt_b     = (const float*)d_in[9];
    const float* A_log    = (const float*)d_in[10];
    const float* D_skip   = (const float*)d_in[11];
    const float* out_w    = (const float*)d_in[12];
    const float* normf_w  = (const float*)d_in[13];
    float* out = (float*)d_out;

    char* ws = (char*)d_ws;
    float* residual = (float*)(ws);                      //  6,291,456
    bf16*  hn16     = (bf16*)(ws + 6291456);             //  3,145,728
    bf16*  xz16     = (bf16*)(ws + 9437184);             // 12,582,912
    float* xdbl     = (float*)(ws + 22020096);           //  2,097,152 (2 buffers)
    bf16*  ybuf16   = (bf16*)(ws + 24117248);            //  6,291,456
    float* Psum     = (float*)(ws + 30408704);           // 12,582,912
    float* Ssum     = (float*)(ws + 42991616);           // 12,582,912
    float* Hin      = (float*)(ws + 55574528);           // 12,582,912
    bf16*  in16     = (bf16*)(ws + 68157440);            // 18,874,368
    bf16*  out16    = (bf16*)(ws + 87031808);            //  9,437,184
    bf16*  xp16     = (bf16*)(ws + 96468992);            //  1,572,864
                                                         // total 98,041,856 bytes

    init_kernel<<<66560, 256, 0, stream>>>(seq, emb, in_w, out_w, xp_w,
                                           residual, in16, out16, xp16, xdbl);

    for (int i = 0; i < NLAYER; ++i) {
        float* xd_cur = xdbl + (size_t)(i & 1) * (BSZ * LSEQ * XDSTR);
        float* xd_nxt = xdbl + (size_t)((i + 1) & 1) * (BSZ * LSEQ * XDSTR);
        const float* cw = conv_w + (size_t)i * DINNER * DCONV;
        const float* cb = conv_b + (size_t)i * DINNER;
        const float* dw = dt_w + (size_t)i * DINNER * DTRANK;
        const float* db = dt_b + (size_t)i * DINNER;
        const float* al = A_log + (size_t)i * DINNER * DSTATE;

        rmsnorm_kernel<<<BSZ * LSEQ, 256, 0, stream>>>(residual, norm_w + (size_t)i * DMODEL, hn16);
        // in_proj: xz16(2048x3072) = hn16 @ in16[i]^T  (grid 768, 3 blocks/CU)
        gemm_128x64_g<<<dim3(16, 48), 256, 0, stream>>>(
            hn16, DMODEL, in16 + (size_t)i * 3072 * DMODEL, DMODEL, xz16, XZLD, DMODEL);
        // x_proj (conv+silu fused A, async B): xdbl(2048x128) f32, split-K=8 (grid 512)
        xproj_conv_gemm<<<dim3(32, 2, 8), 256, 0, stream>>>(
            xz16, cw, cb, xp16 + (size_t)i * 128 * DINNER, xd_cur);
        scan_phaseA<<<768, 256, 0, stream>>>(
            xz16, cw, cb, xd_cur, dw, db, al, Psum, Ssum, xd_nxt);
        scan_phaseB<<<192, 256, 0, stream>>>(Psum, Ssum, Hin);
        scan_phaseC<<<768, 256, 0, stream>>>(
            xz16, cw, cb, xd_cur, dw, db, al, D_skip + (size_t)i * DINNER, Hin, ybuf16);
        // out_proj: residual += ybuf16 @ out16[i]^T, split-K=2 (grid 768)
        gemm_64_atomic_g<<<dim3(32, 12, 2), 256, 0, stream>>>(
            ybuf16, DINNER, out16 + (size_t)i * DMODEL * DINNER, DINNER, residual, DMODEL, DINNER);
    }

    final_kernel<<<BSZ, 256, 0, stream>>>(residual, mask, normf_w, out);
}

// Round 5
// 791.191 us; speedup vs baseline: 1.1790x; 1.0934x over previous
//
#include <hip/hip_runtime.h>
#include <hip/hip_bf16.h>

// ---- problem constants ----
#define BSZ 2
#define LSEQ 1024
#define DMODEL 768
#define NLAYER 4
#define DINNER 1536
#define DSTATE 16
#define DCONV 4
#define DTRANK 48
#define NCHUNK 64
#define CLEN 16
#define XDSTR 128
#define XZLD (2 * DINNER)

typedef __bf16 bf16x8_t __attribute__((ext_vector_type(8)));
typedef float f32x4_t __attribute__((ext_vector_type(4)));
typedef unsigned short u16x8_t __attribute__((ext_vector_type(8)));
typedef __hip_bfloat16 bf16;

__device__ inline float bfbits2f(unsigned short u) {
    unsigned int x = ((unsigned int)u) << 16;
    return __builtin_bit_cast(float, x);
}
__device__ inline unsigned short f2bfbits(float f) {
    return __builtin_bit_cast(unsigned short, (__bf16)f);
}

// async global->LDS, 16B per lane. dest = wave-uniform base + lane*16 (HW).
__device__ __forceinline__ void gload16(const bf16* g, bf16* l) {
    __builtin_amdgcn_global_load_lds(
        (const __attribute__((address_space(1))) unsigned int*)g,
        (__attribute__((address_space(3))) unsigned int*)l,
        16, 0, 0);
}

__device__ inline float block_reduce_sum(float v, float* sbuf) {
    __syncthreads();
    #pragma unroll
    for (int o = 32; o > 0; o >>= 1) v += __shfl_down(v, o, 64);
    int wid = threadIdx.x >> 6;
    int lane = threadIdx.x & 63;
    if (lane == 0) sbuf[wid] = v;
    __syncthreads();
    if (threadIdx.x == 0) sbuf[0] = (sbuf[0] + sbuf[1]) + (sbuf[2] + sbuf[3]);
    __syncthreads();
    return sbuf[0];
}

// ---------------- init: weight prep f32->bf16 + embedding + xdbl zero ----------------
#define PN1 (NLAYER * 3072 * 768)
#define PN2 (NLAYER * 768 * 1536)
#define PN3 (NLAYER * 128 * 1536)
#define PN4 (BSZ * LSEQ * DMODEL)
#define PN5 (2 * BSZ * LSEQ * XDSTR)
// total = 17,039,360 -> grid 66560
__global__ __launch_bounds__(256) void init_kernel(
    const int* __restrict__ seq, const float* __restrict__ emb,
    const float* __restrict__ in_w, const float* __restrict__ out_w,
    const float* __restrict__ xp_w,
    float* __restrict__ residual, bf16* __restrict__ in16,
    bf16* __restrict__ out16, bf16* __restrict__ xp16, float* __restrict__ xdbl2) {
    int idx = blockIdx.x * 256 + threadIdx.x;
    if (idx < PN1) { in16[idx] = __float2bfloat16(in_w[idx]); return; }
    idx -= PN1;
    if (idx < PN2) { out16[idx] = __float2bfloat16(out_w[idx]); return; }
    idx -= PN2;
    if (idx < PN3) {
        int l = idx / (128 * DINNER);
        int r = idx - l * (128 * DINNER);
        int e = r / DINNER;
        int k = r - e * DINNER;
        xp16[idx] = (e < 80) ? __float2bfloat16(xp_w[((size_t)l * 80 + e) * DINNER + k])
                             : __float2bfloat16(0.f);
        return;
    }
    idx -= PN3;
    if (idx < PN4) {
        int bl = idx / DMODEL;
        int dd = idx - bl * DMODEL;
        residual[idx] = emb[(size_t)seq[bl] * DMODEL + dd];
        return;
    }
    idx -= PN4;
    xdbl2[idx] = 0.f;
}

// ---------------- rmsnorm (layer 0) -> bf16 ----------------
__global__ __launch_bounds__(256) void rmsnorm_kernel(
    const float* __restrict__ res, const float* __restrict__ w, bf16* __restrict__ out) {
    __shared__ float sbuf[8];
    int row = blockIdx.x;
    const float* x = res + (size_t)row * DMODEL;
    float ss = 0.f;
    for (int i = threadIdx.x; i < DMODEL; i += 256) { float v = x[i]; ss += v * v; }
    ss = block_reduce_sum(ss, sbuf);
    float scale = rsqrtf(ss / (float)DMODEL + 1e-5f);
    for (int i = threadIdx.x; i < DMODEL; i += 256)
        out[(size_t)row * DMODEL + i] = __float2bfloat16(x[i] * scale * w[i]);
}

// ---------------- rmsnorm with residual += P0+P1 write-back (layers 1..3) ----------------
__global__ __launch_bounds__(256) void rmsnorm_acc_kernel(
    float* __restrict__ res, const float* __restrict__ p0, const float* __restrict__ p1,
    const float* __restrict__ w, bf16* __restrict__ out) {
    __shared__ float sbuf[8];
    int row = blockIdx.x;
    size_t base = (size_t)row * DMODEL;
    float ss = 0.f;
    for (int i = threadIdx.x; i < DMODEL; i += 256) {
        float v = res[base + i] + p0[base + i] + p1[base + i];
        res[base + i] = v;
        ss += v * v;
    }
    ss = block_reduce_sum(ss, sbuf);
    float scale = rsqrtf(ss / (float)DMODEL + 1e-5f);
    for (int i = threadIdx.x; i < DMODEL; i += 256)
        out[base + i] = __float2bfloat16(res[base + i] * scale * w[i]);
}

// ---------------- GEMM 128x64 tile, async gload_lds + XOR swizzle (in_proj) ----------------
__global__ __launch_bounds__(256) void gemm_128x64_g(
    const bf16* __restrict__ A, int lda, const bf16* __restrict__ Bw, int ldb,
    bf16* __restrict__ C16, int ldc, int K) {
    __shared__ bf16 As[128][64];
    __shared__ bf16 Bs[64][64];
    int tid = threadIdx.x;
    int wave = tid >> 6;
    int lane = tid & 63;
    int quad = lane >> 4;
    int l16 = lane & 15;
    int bm = blockIdx.x * 128;
    int bn = blockIdx.y * 64;
    int wm = wave * 32;
    int lr = lane >> 3;
    int lc = (lane & 7) ^ lr;
    int sx = (l16 & 7) << 3;

    f32x4_t acc[2][4];
    #pragma unroll
    for (int i = 0; i < 2; ++i)
        #pragma unroll
        for (int j = 0; j < 4; ++j) acc[i][j] = (f32x4_t){0.f, 0.f, 0.f, 0.f};

    for (int k0 = 0; k0 < K; k0 += 64) {
        #pragma unroll
        for (int i = 0; i < 6; ++i) {
            int ch = wave * 6 + i;
            if (ch < 16) {
                int r = ch * 8 + lr;
                gload16(A + (size_t)(bm + r) * lda + k0 + lc * 8, &As[ch * 8][0]);
            } else {
                int c2 = ch - 16;
                int r = c2 * 8 + lr;
                gload16(Bw + (size_t)(bn + r) * ldb + k0 + lc * 8, &Bs[c2 * 8][0]);
            }
        }
        __syncthreads();
        #pragma unroll
        for (int kk = 0; kk < 64; kk += 32) {
            bf16x8_t af[2], bf[4];
            #pragma unroll
            for (int i = 0; i < 2; ++i)
                af[i] = *(const bf16x8_t*)(&As[wm + i * 16 + l16][(kk + quad * 8) ^ sx]);
            #pragma unroll
            for (int j = 0; j < 4; ++j)
                bf[j] = *(const bf16x8_t*)(&Bs[j * 16 + l16][(kk + quad * 8) ^ sx]);
            #pragma unroll
            for (int i = 0; i < 2; ++i)
                #pragma unroll
                for (int j = 0; j < 4; ++j)
                    acc[i][j] = __builtin_amdgcn_mfma_f32_16x16x32_bf16(af[i], bf[j], acc[i][j], 0, 0, 0);
        }
        __syncthreads();
    }

    int mbase = bm + wm + quad * 4;
    #pragma unroll
    for (int i = 0; i < 2; ++i)
        #pragma unroll
        for (int j = 0; j < 4; ++j) {
            int n = bn + j * 16 + l16;
            #pragma unroll
            for (int r = 0; r < 4; ++r)
                C16[(size_t)(mbase + i * 16 + r) * ldc + n] = __float2bfloat16(acc[i][j][r]);
        }
}

// ---------------- GEMM 64x64 tile, async staging, split-K atomicAdd f32 (x_proj) ----------------
__global__ __launch_bounds__(256) void gemm_64_atomic_g(
    const bf16* __restrict__ A, int lda, const bf16* __restrict__ Bw, int ldb,
    float* __restrict__ Cf, int ldc, int K) {
    __shared__ bf16 As[64][64];
    __shared__ bf16 Bs[64][64];
    int tid = threadIdx.x;
    int wave = tid >> 6;
    int lane = tid & 63;
    int quad = lane >> 4;
    int l16 = lane & 15;
    int bm = blockIdx.x * 64;
    int bn = blockIdx.y * 64;
    int lr = lane >> 3;
    int lc = (lane & 7) ^ lr;
    int sx = (l16 & 7) << 3;
    int kpb = K / gridDim.z;
    int kbeg = blockIdx.z * kpb;
    int kend = kbeg + kpb;

    f32x4_t acc[4];
    #pragma unroll
    for (int i = 0; i < 4; ++i) acc[i] = (f32x4_t){0.f, 0.f, 0.f, 0.f};

    for (int k0 = kbeg; k0 < kend; k0 += 64) {
        #pragma unroll
        for (int i = 0; i < 4; ++i) {
            int ch = wave * 4 + i;
            if (ch < 8) {
                int r = ch * 8 + lr;
                gload16(A + (size_t)(bm + r) * lda + k0 + lc * 8, &As[ch * 8][0]);
            } else {
                int c2 = ch - 8;
                int r = c2 * 8 + lr;
                gload16(Bw + (size_t)(bn + r) * ldb + k0 + lc * 8, &Bs[c2 * 8][0]);
            }
        }
        __syncthreads();
        #pragma unroll
        for (int kk = 0; kk < 64; kk += 32) {
            bf16x8_t af = *(const bf16x8_t*)(&As[wave * 16 + l16][(kk + quad * 8) ^ sx]);
            #pragma unroll
            for (int i = 0; i < 4; ++i) {
                bf16x8_t bv = *(const bf16x8_t*)(&Bs[i * 16 + l16][(kk + quad * 8) ^ sx]);
                acc[i] = __builtin_amdgcn_mfma_f32_16x16x32_bf16(af, bv, acc[i], 0, 0, 0);
            }
        }
        __syncthreads();
    }

    int m0 = bm + wave * 16 + quad * 4;
    #pragma unroll
    for (int i = 0; i < 4; ++i) {
        int n = bn + i * 16 + l16;
        #pragma unroll
        for (int r = 0; r < 4; ++r)
            atomicAdd(&Cf[(size_t)(m0 + r) * ldc + n], acc[i][r]);
    }
}

// ---------------- GEMM 64x64 tile, split-K=2, plain partial stores (out_proj) ----------------
__global__ __launch_bounds__(256) void gemm_64_part_g(
    const bf16* __restrict__ A, int lda, const bf16* __restrict__ Bw, int ldb,
    float* __restrict__ P0, float* __restrict__ P1, int ldc, int K) {
    __shared__ bf16 As[64][64];
    __shared__ bf16 Bs[64][64];
    int tid = threadIdx.x;
    int wave = tid >> 6;
    int lane = tid & 63;
    int quad = lane >> 4;
    int l16 = lane & 15;
    int bm = blockIdx.x * 64;
    int bn = blockIdx.y * 64;
    int lr = lane >> 3;
    int lc = (lane & 7) ^ lr;
    int sx = (l16 & 7) << 3;
    int kpb = K / gridDim.z;
    int kbeg = blockIdx.z * kpb;
    int kend = kbeg + kpb;
    float* Cf = (blockIdx.z == 0) ? P0 : P1;

    f32x4_t acc[4];
    #pragma unroll
    for (int i = 0; i < 4; ++i) acc[i] = (f32x4_t){0.f, 0.f, 0.f, 0.f};

    for (int k0 = kbeg; k0 < kend; k0 += 64) {
        #pragma unroll
        for (int i = 0; i < 4; ++i) {
            int ch = wave * 4 + i;
            if (ch < 8) {
                int r = ch * 8 + lr;
                gload16(A + (size_t)(bm + r) * lda + k0 + lc * 8, &As[ch * 8][0]);
            } else {
                int c2 = ch - 8;
                int r = c2 * 8 + lr;
                gload16(Bw + (size_t)(bn + r) * ldb + k0 + lc * 8, &Bs[c2 * 8][0]);
            }
        }
        __syncthreads();
        #pragma unroll
        for (int kk = 0; kk < 64; kk += 32) {
            bf16x8_t af = *(const bf16x8_t*)(&As[wave * 16 + l16][(kk + quad * 8) ^ sx]);
            #pragma unroll
            for (int i = 0; i < 4; ++i) {
                bf16x8_t bv = *(const bf16x8_t*)(&Bs[i * 16 + l16][(kk + quad * 8) ^ sx]);
                acc[i] = __builtin_amdgcn_mfma_f32_16x16x32_bf16(af, bv, acc[i], 0, 0, 0);
            }
        }
        __syncthreads();
    }

    int m0 = bm + wave * 16 + quad * 4;
    #pragma unroll
    for (int i = 0; i < 4; ++i) {
        int n = bn + i * 16 + l16;
        #pragma unroll
        for (int r = 0; r < 4; ++r)
            Cf[(size_t)(m0 + r) * ldc + n] = acc[i][r];
    }
}

// ---------------- u = silu(conv4(x)+cb), vectorized x8 (throughput kernel) ----------------
#define UCHUNKS (DINNER / 8)   // 192
__global__ __launch_bounds__(256) void usilu_kernel(
    const bf16* __restrict__ xz16, const float* __restrict__ cw, const float* __restrict__ cb,
    bf16* __restrict__ u16) {
    int idx = blockIdx.x * 256 + threadIdx.x;          // < 2048*192
    int row = idx / UCHUNKS;
    int d0 = (idx - row * UCHUNKS) * 8;
    int l = row & (LSEQ - 1);
    const u16x8_t Z8 = (u16x8_t){0, 0, 0, 0, 0, 0, 0, 0};
    u16x8_t xa[4];
    #pragma unroll
    for (int t = 0; t < 4; ++t)
        xa[t] = (l >= 3 - t) ? *(const u16x8_t*)(xz16 + (size_t)(row - 3 + t) * XZLD + d0) : Z8;
    u16x8_t r;
    #pragma unroll
    for (int j = 0; j < 8; ++j) {
        float4 cwv = *(const float4*)(cw + (size_t)(d0 + j) * 4);
        float a = cb[d0 + j]
            + bfbits2f(xa[0][j]) * cwv.x + bfbits2f(xa[1][j]) * cwv.y
            + bfbits2f(xa[2][j]) * cwv.z + bfbits2f(xa[3][j]) * cwv.w;
        a = a / (1.f + __expf(-a));
        r[j] = f2bfbits(a);
    }
    *(u16x8_t*)(u16 + (size_t)row * DINNER + d0) = r;
}

// ---------------- delta from f32 xdbl row (wave-uniform) + per-thread dtw ----------------
__device__ inline float compute_delta(const float* __restrict__ xrow,
                                      const float* __restrict__ dtw, float dtbd) {
    float acc = dtbd;
    #pragma unroll
    for (int j = 0; j < DTRANK; j += 4) {
        float4 xv = *(const float4*)(xrow + j);
        acc += xv.x * dtw[j] + xv.y * dtw[j + 1] + xv.z * dtw[j + 2] + xv.w * dtw[j + 3];
    }
    return (acc > 20.f) ? acc : log1pf(__expf(acc));
}

// ================= chunked scan (u precomputed) =================
__global__ __launch_bounds__(256) void scan_phaseA(
    const bf16* __restrict__ u16, const float* __restrict__ xdbl,
    const float* __restrict__ dt_w, const float* __restrict__ dt_b,
    const float* __restrict__ A_log,
    float* __restrict__ Psum, float* __restrict__ Ssum,
    float* __restrict__ xd_next) {
    int gtid = blockIdx.x * 256 + threadIdx.x;
    int d = gtid % DINNER;
    int c = (gtid / DINNER) % NCHUNK;
    int b = gtid / (DINNER * NCHUNK);
    float dtw[DTRANK];
    #pragma unroll
    for (int j = 0; j < DTRANK; j += 4)
        *(float4*)(dtw + j) = *(const float4*)(dt_w + (size_t)d * DTRANK + j);
    float dtbd = dt_b[d];
    float Av[DSTATE], P[DSTATE], S[DSTATE];
    #pragma unroll
    for (int s = 0; s < DSTATE; ++s) {
        Av[s] = -__expf(A_log[d * DSTATE + s]);
        P[s] = 1.f; S[s] = 0.f;
    }
    int t0 = c * CLEN;
    int rowb = b * LSEQ;
    for (int i = 0; i < CLEN; ++i) {
        int row = rowb + t0 + i;
        const float* xrow = xdbl + (size_t)row * XDSTR;
        float dl = compute_delta(xrow, dtw, dtbd);
        float u = __bfloat162float(u16[(size_t)row * DINNER + d]);
        float bt = dl * u;
        const float4* Bp = (const float4*)(xrow + DTRANK);
        float4 B0 = Bp[0], B1 = Bp[1], B2 = Bp[2], B3 = Bp[3];
        float Bv[DSTATE] = {B0.x,B0.y,B0.z,B0.w, B1.x,B1.y,B1.z,B1.w,
                            B2.x,B2.y,B2.z,B2.w, B3.x,B3.y,B3.z,B3.w};
        #pragma unroll
        for (int s = 0; s < DSTATE; ++s) {
            float a = __expf(dl * Av[s]);
            P[s] *= a;
            S[s] = a * S[s] + bt * Bv[s];
        }
    }
    size_t base = ((size_t)(b * NCHUNK + c) * DSTATE) * DINNER + d;
    #pragma unroll
    for (int s = 0; s < DSTATE; ++s) {
        Psum[base + (size_t)s * DINNER] = P[s];
        Ssum[base + (size_t)s * DINNER] = S[s];
    }
    // zero next layer's xdbl buffer (its last reader finished 2+ kernels ago)
    for (int z = gtid; z < BSZ * LSEQ * XDSTR; z += BSZ * NCHUNK * DINNER)
        xd_next[z] = 0.f;
}

__global__ __launch_bounds__(256) void scan_phaseB(
    const float* __restrict__ Psum, const float* __restrict__ Ssum,
    float* __restrict__ Hin) {
    int gtid = blockIdx.x * 256 + threadIdx.x;
    int d = gtid % DINNER;
    int s = (gtid / DINNER) % DSTATE;
    int b = gtid / (DINNER * DSTATE);
    float h = 0.f;
    for (int c = 0; c < NCHUNK; ++c) {
        size_t idx = ((size_t)(b * NCHUNK + c) * DSTATE + s) * DINNER + d;
        Hin[idx] = h;
        h = Psum[idx] * h + Ssum[idx];
    }
}

// reads u from uy16, overwrites it with y (same (row,d) owner -> race-free)
__global__ __launch_bounds__(256) void scan_phaseC(
    bf16* __restrict__ uy16, const bf16* __restrict__ xz16,
    const float* __restrict__ xdbl,
    const float* __restrict__ dt_w, const float* __restrict__ dt_b,
    const float* __restrict__ A_log, const float* __restrict__ D_skip,
    const float* __restrict__ Hin) {
    int gtid = blockIdx.x * 256 + threadIdx.x;
    int d = gtid % DINNER;
    int c = (gtid / DINNER) % NCHUNK;
    int b = gtid / (DINNER * NCHUNK);
    float dtw[DTRANK];
    #pragma unroll
    for (int j = 0; j < DTRANK; j += 4)
        *(float4*)(dtw + j) = *(const float4*)(dt_w + (size_t)d * DTRANK + j);
    float dtbd = dt_b[d];
    float Av[DSTATE], h[DSTATE];
    size_t base = ((size_t)(b * NCHUNK + c) * DSTATE) * DINNER + d;
    #pragma unroll
    for (int s = 0; s < DSTATE; ++s) {
        Av[s] = -__expf(A_log[d * DSTATE + s]);
        h[s] = Hin[base + (size_t)s * DINNER];
    }
    float Dsk = D_skip[d];
    int t0 = c * CLEN;
    int rowb = b * LSEQ;
    for (int i = 0; i < CLEN; ++i) {
        int row = rowb + t0 + i;
        const float* xrow = xdbl + (size_t)row * XDSTR;
        float dl = compute_delta(xrow, dtw, dtbd);
        float u = __bfloat162float(uy16[(size_t)row * DINNER + d]);
        float bt = dl * u;
        const float4* Bp = (const float4*)(xrow + DTRANK);
        float4 B0 = Bp[0], B1 = Bp[1], B2 = Bp[2], B3 = Bp[3];
        const float4* Cp = (const float4*)(xrow + DTRANK + DSTATE);
        float4 C0 = Cp[0], C1 = Cp[1], C2 = Cp[2], C3 = Cp[3];
        float Bv[DSTATE] = {B0.x,B0.y,B0.z,B0.w, B1.x,B1.y,B1.z,B1.w,
                            B2.x,B2.y,B2.z,B2.w, B3.x,B3.y,B3.z,B3.w};
        float Cv[DSTATE] = {C0.x,C0.y,C0.z,C0.w, C1.x,C1.y,C1.z,C1.w,
                            C2.x,C2.y,C2.z,C2.w, C3.x,C3.y,C3.z,C3.w};
        float acc = 0.f;
        #pragma unroll
        for (int s = 0; s < DSTATE; ++s) {
            float a = __expf(dl * Av[s]);
            h[s] = a * h[s] + bt * Bv[s];
            acc += h[s] * Cv[s];
        }
        float zv = __bfloat162float(xz16[(size_t)row * XZLD + DINNER + d]);
        float sz = zv / (1.f + __expf(-zv));
        uy16[(size_t)row * DINNER + d] = __float2bfloat16((acc + u * Dsk) * sz);
    }
}

// ---------------- final: last-token rmsnorm over res + P0 + P1 ----------------
__global__ __launch_bounds__(256) void final_acc_kernel(
    const float* __restrict__ res, const float* __restrict__ p0, const float* __restrict__ p1,
    const int* __restrict__ mask, const float* __restrict__ w, float* __restrict__ out) {
    __shared__ float sbuf[8];
    int b = blockIdx.x;
    float cnt = 0.f;
    for (int i = threadIdx.x; i < LSEQ; i += 256) cnt += (float)mask[b * LSEQ + i];
    cnt = block_reduce_sum(cnt, sbuf);
    int last = (int)cnt - 1;
    size_t base = ((size_t)b * LSEQ + last) * DMODEL;
    float ss = 0.f;
    for (int i = threadIdx.x; i < DMODEL; i += 256) {
        float v = res[base + i] + p0[base + i] + p1[base + i];
        ss += v * v;
    }
    ss = block_reduce_sum(ss, sbuf);
    float scale = rsqrtf(ss / (float)DMODEL + 1e-5f);
    for (int i = threadIdx.x; i < DMODEL; i += 256) {
        float v = res[base + i] + p0[base + i] + p1[base + i];
        out[b * DMODEL + i] = v * scale * w[i];
    }
}

extern "C" void kernel_launch(void* const* d_in, const int* in_sizes, int n_in,
                              void* d_out, int out_size, void* d_ws, size_t ws_size,
                              hipStream_t stream) {
    const int*   seq      = (const int*)d_in[0];
    const int*   mask     = (const int*)d_in[1];
    const float* emb      = (const float*)d_in[2];
    const float* norm_w   = (const float*)d_in[3];
    const float* in_w     = (const float*)d_in[4];
    const float* conv_w   = (const float*)d_in[5];
    const float* conv_b   = (const float*)d_in[6];
    const float* xp_w     = (const float*)d_in[7];
    const float* dt_w     = (const float*)d_in[8];
    const float* dt_b     = (const float*)d_in[9];
    const float* A_log    = (const float*)d_in[10];
    const float* D_skip   = (const float*)d_in[11];
    const float* out_w    = (const float*)d_in[12];
    const float* normf_w  = (const float*)d_in[13];
    float* out = (float*)d_out;

    char* ws = (char*)d_ws;
    float* residual = (float*)(ws);                      //  6,291,456
    bf16*  hn16     = (bf16*)(ws + 6291456);             //  3,145,728
    bf16*  xz16     = (bf16*)(ws + 9437184);             // 12,582,912
    float* xdbl     = (float*)(ws + 22020096);           //  2,097,152 (2 buffers)
    bf16*  uy16     = (bf16*)(ws + 24117248);            //  6,291,456 (u, then y in-place)
    float* Psum     = (float*)(ws + 30408704);           // 12,582,912 (also out_proj P0)
    float* Ssum     = (float*)(ws + 42991616);           // 12,582,912 (also out_proj P1)
    float* Hin      = (float*)(ws + 55574528);           // 12,582,912
    bf16*  in16     = (bf16*)(ws + 68157440);            // 18,874,368
    bf16*  out16    = (bf16*)(ws + 87031808);            //  9,437,184
    bf16*  xp16     = (bf16*)(ws + 96468992);            //  1,572,864
                                                         // total 98,041,856 bytes
    float* P0 = Psum;   // out_proj partials (lifetime: out_proj(i) -> rms_acc(i+1))
    float* P1 = Ssum;

    init_kernel<<<66560, 256, 0, stream>>>(seq, emb, in_w, out_w, xp_w,
                                           residual, in16, out16, xp16, xdbl);

    for (int i = 0; i < NLAYER; ++i) {
        float* xd_cur = xdbl + (size_t)(i & 1) * (BSZ * LSEQ * XDSTR);
        float* xd_nxt = xdbl + (size_t)((i + 1) & 1) * (BSZ * LSEQ * XDSTR);
        const float* cw = conv_w + (size_t)i * DINNER * DCONV;
        const float* cb = conv_b + (size_t)i * DINNER;
        const float* dw = dt_w + (size_t)i * DINNER * DTRANK;
        const float* db = dt_b + (size_t)i * DINNER;
        const float* al = A_log + (size_t)i * DINNER * DSTATE;

        if (i == 0)
            rmsnorm_kernel<<<BSZ * LSEQ, 256, 0, stream>>>(
                residual, norm_w, hn16);
        else
            rmsnorm_acc_kernel<<<BSZ * LSEQ, 256, 0, stream>>>(
                residual, P0, P1, norm_w + (size_t)i * DMODEL, hn16);
        // in_proj: xz16(2048x3072) = hn16 @ in16[i]^T  (grid 768, 3 blocks/CU)
        gemm_128x64_g<<<dim3(16, 48), 256, 0, stream>>>(
            hn16, DMODEL, in16 + (size_t)i * 3072 * DMODEL, DMODEL, xz16, XZLD, DMODEL);
        // u = silu(conv(x)+cb): throughput kernel, writes uy16
        usilu_kernel<<<(BSZ * LSEQ * UCHUNKS) / 256, 256, 0, stream>>>(xz16, cw, cb, uy16);
        // x_proj: xdbl(2048x128) f32 = u @ xp16[i]^T, split-K=8 atomic (grid 512)
        gemm_64_atomic_g<<<dim3(32, 2, 8), 256, 0, stream>>>(
            uy16, DINNER, xp16 + (size_t)i * 128 * DINNER, DINNER, xd_cur, XDSTR, DINNER);
        scan_phaseA<<<768, 256, 0, stream>>>(
            uy16, xd_cur, dw, db, al, Psum, Ssum, xd_nxt);
        scan_phaseB<<<192, 256, 0, stream>>>(Psum, Ssum, Hin);
        scan_phaseC<<<768, 256, 0, stream>>>(
            uy16, xz16, xd_cur, dw, db, al, D_skip + (size_t)i * DINNER, Hin);
        // out_proj partials: P0/P1(2048x768) = y @ out16[i]^T, split-K=2, no atomics
        gemm_64_part_g<<<dim3(32, 12, 2), 256, 0, stream>>>(
            uy16, DINNER, out16 + (size_t)i * DMODEL * DINNER, DINNER, P0, P1, DMODEL, DINNER);
    }

    final_acc_kernel<<<BSZ, 256, 0, stream>>>(residual, P0, P1, mask, normf_w, out);
}

// Round 6
// 702.720 us; speedup vs baseline: 1.3274x; 1.1259x over previous
//
#include <hip/hip_runtime.h>
#include <hip/hip_bf16.h>

// ---- problem constants ----
#define BSZ 2
#define LSEQ 1024
#define DMODEL 768
#define NLAYER 4
#define DINNER 1536
#define DSTATE 16
#define DCONV 4
#define DTRANK 48
#define NCHUNK 64
#define CLEN 16
#define XDSTR 128
#define XZLD (2 * DINNER)

typedef __bf16 bf16x8_t __attribute__((ext_vector_type(8)));
typedef float f32x4_t __attribute__((ext_vector_type(4)));
typedef unsigned short u16x8_t __attribute__((ext_vector_type(8)));
typedef __hip_bfloat16 bf16;

__device__ inline float bfbits2f(unsigned short u) {
    unsigned int x = ((unsigned int)u) << 16;
    return __builtin_bit_cast(float, x);
}
__device__ inline unsigned short f2bfbits(float f) {
    return __builtin_bit_cast(unsigned short, (__bf16)f);
}

// async global->LDS, 16B per lane. dest = wave-uniform base + lane*16 (HW).
__device__ __forceinline__ void gload16(const bf16* g, bf16* l) {
    __builtin_amdgcn_global_load_lds(
        (const __attribute__((address_space(1))) unsigned int*)g,
        (__attribute__((address_space(3))) unsigned int*)l,
        16, 0, 0);
}

__device__ inline float block_reduce_sum(float v, float* sbuf) {
    __syncthreads();
    #pragma unroll
    for (int o = 32; o > 0; o >>= 1) v += __shfl_down(v, o, 64);
    int wid = threadIdx.x >> 6;
    int lane = threadIdx.x & 63;
    if (lane == 0) sbuf[wid] = v;
    __syncthreads();
    if (threadIdx.x == 0) sbuf[0] = (sbuf[0] + sbuf[1]) + (sbuf[2] + sbuf[3]);
    __syncthreads();
    return sbuf[0];
}

// ---------------- init: weight prep f32->bf16 + embedding + xdbl zero ----------------
#define PN1 (NLAYER * 3072 * 768)
#define PN2 (NLAYER * 768 * 1536)
#define PN3 (NLAYER * 128 * 1536)
#define PN4 (BSZ * LSEQ * DMODEL)
#define PN5 (2 * BSZ * LSEQ * XDSTR)
// total = 17,039,360 -> grid 66560
__global__ __launch_bounds__(256) void init_kernel(
    const int* __restrict__ seq, const float* __restrict__ emb,
    const float* __restrict__ in_w, const float* __restrict__ out_w,
    const float* __restrict__ xp_w,
    float* __restrict__ residual, bf16* __restrict__ in16,
    bf16* __restrict__ out16, bf16* __restrict__ xp16, float* __restrict__ xdbl2) {
    int idx = blockIdx.x * 256 + threadIdx.x;
    if (idx < PN1) { in16[idx] = __float2bfloat16(in_w[idx]); return; }
    idx -= PN1;
    if (idx < PN2) { out16[idx] = __float2bfloat16(out_w[idx]); return; }
    idx -= PN2;
    if (idx < PN3) {
        int l = idx / (128 * DINNER);
        int r = idx - l * (128 * DINNER);
        int e = r / DINNER;
        int k = r - e * DINNER;
        xp16[idx] = (e < 80) ? __float2bfloat16(xp_w[((size_t)l * 80 + e) * DINNER + k])
                             : __float2bfloat16(0.f);
        return;
    }
    idx -= PN3;
    if (idx < PN4) {
        int bl = idx / DMODEL;
        int dd = idx - bl * DMODEL;
        residual[idx] = emb[(size_t)seq[bl] * DMODEL + dd];
        return;
    }
    idx -= PN4;
    xdbl2[idx] = 0.f;
}

// ---------------- rmsnorm (layer 0) -> bf16 ----------------
__global__ __launch_bounds__(256) void rmsnorm_kernel(
    const float* __restrict__ res, const float* __restrict__ w, bf16* __restrict__ out) {
    __shared__ float sbuf[8];
    int row = blockIdx.x;
    const float* x = res + (size_t)row * DMODEL;
    float ss = 0.f;
    for (int i = threadIdx.x; i < DMODEL; i += 256) { float v = x[i]; ss += v * v; }
    ss = block_reduce_sum(ss, sbuf);
    float scale = rsqrtf(ss / (float)DMODEL + 1e-5f);
    for (int i = threadIdx.x; i < DMODEL; i += 256)
        out[(size_t)row * DMODEL + i] = __float2bfloat16(x[i] * scale * w[i]);
}

// ---------------- rmsnorm with residual += P0..P3 write-back (layers 1..3) ----------------
__global__ __launch_bounds__(256) void rmsnorm_acc_kernel(
    float* __restrict__ res, const float* __restrict__ p0, const float* __restrict__ p1,
    const float* __restrict__ p2, const float* __restrict__ p3,
    const float* __restrict__ w, bf16* __restrict__ out) {
    __shared__ float sbuf[8];
    int row = blockIdx.x;
    size_t base = (size_t)row * DMODEL;
    float ss = 0.f;
    for (int i = threadIdx.x; i < DMODEL; i += 256) {
        float v = res[base + i] + ((p0[base + i] + p1[base + i]) + (p2[base + i] + p3[base + i]));
        res[base + i] = v;
        ss += v * v;
    }
    ss = block_reduce_sum(ss, sbuf);
    float scale = rsqrtf(ss / (float)DMODEL + 1e-5f);
    for (int i = threadIdx.x; i < DMODEL; i += 256)
        out[base + i] = __float2bfloat16(res[base + i] * scale * w[i]);
}

// ---------------- GEMM 128x64 tile, async gload_lds + XOR swizzle (in_proj) ----------------
__global__ __launch_bounds__(256) void gemm_128x64_g(
    const bf16* __restrict__ A, int lda, const bf16* __restrict__ Bw, int ldb,
    bf16* __restrict__ C16, int ldc, int K) {
    __shared__ bf16 As[128][64];
    __shared__ bf16 Bs[64][64];
    int tid = threadIdx.x;
    int wave = tid >> 6;
    int lane = tid & 63;
    int quad = lane >> 4;
    int l16 = lane & 15;
    int bm = blockIdx.x * 128;
    int bn = blockIdx.y * 64;
    int wm = wave * 32;
    int lr = lane >> 3;
    int lc = (lane & 7) ^ lr;
    int sx = (l16 & 7) << 3;

    f32x4_t acc[2][4];
    #pragma unroll
    for (int i = 0; i < 2; ++i)
        #pragma unroll
        for (int j = 0; j < 4; ++j) acc[i][j] = (f32x4_t){0.f, 0.f, 0.f, 0.f};

    for (int k0 = 0; k0 < K; k0 += 64) {
        #pragma unroll
        for (int i = 0; i < 6; ++i) {
            int ch = wave * 6 + i;
            if (ch < 16) {
                int r = ch * 8 + lr;
                gload16(A + (size_t)(bm + r) * lda + k0 + lc * 8, &As[ch * 8][0]);
            } else {
                int c2 = ch - 16;
                int r = c2 * 8 + lr;
                gload16(Bw + (size_t)(bn + r) * ldb + k0 + lc * 8, &Bs[c2 * 8][0]);
            }
        }
        __syncthreads();
        #pragma unroll
        for (int kk = 0; kk < 64; kk += 32) {
            bf16x8_t af[2], bf[4];
            #pragma unroll
            for (int i = 0; i < 2; ++i)
                af[i] = *(const bf16x8_t*)(&As[wm + i * 16 + l16][(kk + quad * 8) ^ sx]);
            #pragma unroll
            for (int j = 0; j < 4; ++j)
                bf[j] = *(const bf16x8_t*)(&Bs[j * 16 + l16][(kk + quad * 8) ^ sx]);
            #pragma unroll
            for (int i = 0; i < 2; ++i)
                #pragma unroll
                for (int j = 0; j < 4; ++j)
                    acc[i][j] = __builtin_amdgcn_mfma_f32_16x16x32_bf16(af[i], bf[j], acc[i][j], 0, 0, 0);
        }
        __syncthreads();
    }

    int mbase = bm + wm + quad * 4;
    #pragma unroll
    for (int i = 0; i < 2; ++i)
        #pragma unroll
        for (int j = 0; j < 4; ++j) {
            int n = bn + j * 16 + l16;
            #pragma unroll
            for (int r = 0; r < 4; ++r)
                C16[(size_t)(mbase + i * 16 + r) * ldc + n] = __float2bfloat16(acc[i][j][r]);
        }
}

// ---------------- GEMM 64x64 tile, async staging, split-K atomicAdd f32 (x_proj) ----------------
__global__ __launch_bounds__(256) void gemm_64_atomic_g(
    const bf16* __restrict__ A, int lda, const bf16* __restrict__ Bw, int ldb,
    float* __restrict__ Cf, int ldc, int K) {
    __shared__ bf16 As[64][64];
    __shared__ bf16 Bs[64][64];
    int tid = threadIdx.x;
    int wave = tid >> 6;
    int lane = tid & 63;
    int quad = lane >> 4;
    int l16 = lane & 15;
    int bm = blockIdx.x * 64;
    int bn = blockIdx.y * 64;
    int lr = lane >> 3;
    int lc = (lane & 7) ^ lr;
    int sx = (l16 & 7) << 3;
    int kpb = K / gridDim.z;
    int kbeg = blockIdx.z * kpb;
    int kend = kbeg + kpb;

    f32x4_t acc[4];
    #pragma unroll
    for (int i = 0; i < 4; ++i) acc[i] = (f32x4_t){0.f, 0.f, 0.f, 0.f};

    for (int k0 = kbeg; k0 < kend; k0 += 64) {
        #pragma unroll
        for (int i = 0; i < 4; ++i) {
            int ch = wave * 4 + i;
            if (ch < 8) {
                int r = ch * 8 + lr;
                gload16(A + (size_t)(bm + r) * lda + k0 + lc * 8, &As[ch * 8][0]);
            } else {
                int c2 = ch - 8;
                int r = c2 * 8 + lr;
                gload16(Bw + (size_t)(bn + r) * ldb + k0 + lc * 8, &Bs[c2 * 8][0]);
            }
        }
        __syncthreads();
        #pragma unroll
        for (int kk = 0; kk < 64; kk += 32) {
            bf16x8_t af = *(const bf16x8_t*)(&As[wave * 16 + l16][(kk + quad * 8) ^ sx]);
            #pragma unroll
            for (int i = 0; i < 4; ++i) {
                bf16x8_t bv = *(const bf16x8_t*)(&Bs[i * 16 + l16][(kk + quad * 8) ^ sx]);
                acc[i] = __builtin_amdgcn_mfma_f32_16x16x32_bf16(af, bv, acc[i], 0, 0, 0);
            }
        }
        __syncthreads();
    }

    int m0 = bm + wave * 16 + quad * 4;
    #pragma unroll
    for (int i = 0; i < 4; ++i) {
        int n = bn + i * 16 + l16;
        #pragma unroll
        for (int r = 0; r < 4; ++r)
            atomicAdd(&Cf[(size_t)(m0 + r) * ldc + n], acc[i][r]);
    }
}

// ---------------- GEMM 128x64 tile, split-K=4, plain partial stores (out_proj) ----------------
__global__ __launch_bounds__(256) void gemm_128x64_part_g(
    const bf16* __restrict__ A, int lda, const bf16* __restrict__ Bw, int ldb,
    float* __restrict__ P0, float* __restrict__ P1,
    float* __restrict__ P2, float* __restrict__ P3, int ldc, int K) {
    __shared__ bf16 As[128][64];
    __shared__ bf16 Bs[64][64];
    int tid = threadIdx.x;
    int wave = tid >> 6;
    int lane = tid & 63;
    int quad = lane >> 4;
    int l16 = lane & 15;
    int bm = blockIdx.x * 128;
    int bn = blockIdx.y * 64;
    int wm = wave * 32;
    int lr = lane >> 3;
    int lc = (lane & 7) ^ lr;
    int sx = (l16 & 7) << 3;
    int kpb = K / 4;                      // gridDim.z == 4
    int kbeg = blockIdx.z * kpb;
    int kend = kbeg + kpb;
    float* Cf = (blockIdx.z == 0) ? P0 : (blockIdx.z == 1) ? P1 : (blockIdx.z == 2) ? P2 : P3;

    f32x4_t acc[2][4];
    #pragma unroll
    for (int i = 0; i < 2; ++i)
        #pragma unroll
        for (int j = 0; j < 4; ++j) acc[i][j] = (f32x4_t){0.f, 0.f, 0.f, 0.f};

    for (int k0 = kbeg; k0 < kend; k0 += 64) {
        #pragma unroll
        for (int i = 0; i < 6; ++i) {
            int ch = wave * 6 + i;
            if (ch < 16) {
                int r = ch * 8 + lr;
                gload16(A + (size_t)(bm + r) * lda + k0 + lc * 8, &As[ch * 8][0]);
            } else {
                int c2 = ch - 16;
                int r = c2 * 8 + lr;
                gload16(Bw + (size_t)(bn + r) * ldb + k0 + lc * 8, &Bs[c2 * 8][0]);
            }
        }
        __syncthreads();
        #pragma unroll
        for (int kk = 0; kk < 64; kk += 32) {
            bf16x8_t af[2], bf[4];
            #pragma unroll
            for (int i = 0; i < 2; ++i)
                af[i] = *(const bf16x8_t*)(&As[wm + i * 16 + l16][(kk + quad * 8) ^ sx]);
            #pragma unroll
            for (int j = 0; j < 4; ++j)
                bf[j] = *(const bf16x8_t*)(&Bs[j * 16 + l16][(kk + quad * 8) ^ sx]);
            #pragma unroll
            for (int i = 0; i < 2; ++i)
                #pragma unroll
                for (int j = 0; j < 4; ++j)
                    acc[i][j] = __builtin_amdgcn_mfma_f32_16x16x32_bf16(af[i], bf[j], acc[i][j], 0, 0, 0);
        }
        __syncthreads();
    }

    int mbase = bm + wm + quad * 4;
    #pragma unroll
    for (int i = 0; i < 2; ++i)
        #pragma unroll
        for (int j = 0; j < 4; ++j) {
            int n = bn + j * 16 + l16;
            #pragma unroll
            for (int r = 0; r < 4; ++r)
                Cf[(size_t)(mbase + i * 16 + r) * ldc + n] = acc[i][j][r];
        }
}

// ---------------- u = silu(conv4(x)+cb), vectorized x8 (throughput kernel) ----------------
#define UCHUNKS (DINNER / 8)   // 192
__global__ __launch_bounds__(256) void usilu_kernel(
    const bf16* __restrict__ xz16, const float* __restrict__ cw, const float* __restrict__ cb,
    bf16* __restrict__ u16) {
    int idx = blockIdx.x * 256 + threadIdx.x;          // < 2048*192
    int row = idx / UCHUNKS;
    int d0 = (idx - row * UCHUNKS) * 8;
    int l = row & (LSEQ - 1);
    const u16x8_t Z8 = (u16x8_t){0, 0, 0, 0, 0, 0, 0, 0};
    u16x8_t xa[4];
    #pragma unroll
    for (int t = 0; t < 4; ++t)
        xa[t] = (l >= 3 - t) ? *(const u16x8_t*)(xz16 + (size_t)(row - 3 + t) * XZLD + d0) : Z8;
    u16x8_t r;
    #pragma unroll
    for (int j = 0; j < 8; ++j) {
        float4 cwv = *(const float4*)(cw + (size_t)(d0 + j) * 4);
        float a = cb[d0 + j]
            + bfbits2f(xa[0][j]) * cwv.x + bfbits2f(xa[1][j]) * cwv.y
            + bfbits2f(xa[2][j]) * cwv.z + bfbits2f(xa[3][j]) * cwv.w;
        a = a / (1.f + __expf(-a));
        r[j] = f2bfbits(a);
    }
    *(u16x8_t*)(u16 + (size_t)row * DINNER + d0) = r;
}

// ---------------- delta from f32 xdbl row (wave-uniform) + per-thread dtw ----------------
__device__ inline float compute_delta(const float* __restrict__ xrow,
                                      const float* __restrict__ dtw, float dtbd) {
    float acc = dtbd;
    #pragma unroll
    for (int j = 0; j < DTRANK; j += 4) {
        float4 xv = *(const float4*)(xrow + j);
        acc += xv.x * dtw[j] + xv.y * dtw[j + 1] + xv.z * dtw[j + 2] + xv.w * dtw[j + 3];
    }
    return (acc > 20.f) ? acc : log1pf(__expf(acc));
}

// ================= chunked scan (u precomputed; delta stored for phase C) =================
__global__ __launch_bounds__(256) void scan_phaseA(
    const bf16* __restrict__ u16, const float* __restrict__ xdbl,
    const float* __restrict__ dt_w, const float* __restrict__ dt_b,
    const float* __restrict__ A_log,
    float* __restrict__ Psum, float* __restrict__ Ssum,
    float* __restrict__ Dbuf,          // per-(row,d) delta, reused Hin space
    float* __restrict__ xd_next) {
    int gtid = blockIdx.x * 256 + threadIdx.x;
    int d = gtid % DINNER;
    int c = (gtid / DINNER) % NCHUNK;
    int b = gtid / (DINNER * NCHUNK);
    float dtw[DTRANK];
    #pragma unroll
    for (int j = 0; j < DTRANK; j += 4)
        *(float4*)(dtw + j) = *(const float4*)(dt_w + (size_t)d * DTRANK + j);
    float dtbd = dt_b[d];
    float Av[DSTATE], P[DSTATE], S[DSTATE];
    #pragma unroll
    for (int s = 0; s < DSTATE; ++s) {
        Av[s] = -__expf(A_log[d * DSTATE + s]);
        P[s] = 1.f; S[s] = 0.f;
    }
    int t0 = c * CLEN;
    int rowb = b * LSEQ;
    for (int i = 0; i < CLEN; ++i) {
        int row = rowb + t0 + i;
        const float* xrow = xdbl + (size_t)row * XDSTR;
        float dl = compute_delta(xrow, dtw, dtbd);
        Dbuf[(size_t)row * DINNER + d] = dl;
        float u = __bfloat162float(u16[(size_t)row * DINNER + d]);
        float bt = dl * u;
        const float4* Bp = (const float4*)(xrow + DTRANK);
        float4 B0 = Bp[0], B1 = Bp[1], B2 = Bp[2], B3 = Bp[3];
        float Bv[DSTATE] = {B0.x,B0.y,B0.z,B0.w, B1.x,B1.y,B1.z,B1.w,
                            B2.x,B2.y,B2.z,B2.w, B3.x,B3.y,B3.z,B3.w};
        #pragma unroll
        for (int s = 0; s < DSTATE; ++s) {
            float a = __expf(dl * Av[s]);
            P[s] *= a;
            S[s] = a * S[s] + bt * Bv[s];
        }
    }
    size_t base = ((size_t)(b * NCHUNK + c) * DSTATE) * DINNER + d;
    #pragma unroll
    for (int s = 0; s < DSTATE; ++s) {
        Psum[base + (size_t)s * DINNER] = P[s];
        Ssum[base + (size_t)s * DINNER] = S[s];
    }
    // zero next layer's xdbl buffer (its last reader finished 2+ kernels ago)
    for (int z = gtid; z < BSZ * LSEQ * XDSTR; z += BSZ * NCHUNK * DINNER)
        xd_next[z] = 0.f;
}

// in-place exclusive prefix: Psum[idx] := h_before (chunk-incoming state)
__global__ __launch_bounds__(256) void scan_phaseB(
    float* __restrict__ Psum, const float* __restrict__ Ssum) {
    int gtid = blockIdx.x * 256 + threadIdx.x;
    int d = gtid % DINNER;
    int s = (gtid / DINNER) % DSTATE;
    int b = gtid / (DINNER * DSTATE);
    float h = 0.f;
    for (int c = 0; c < NCHUNK; ++c) {
        size_t idx = ((size_t)(b * NCHUNK + c) * DSTATE + s) * DINNER + d;
        float p = Psum[idx];
        Psum[idx] = h;
        h = p * h + Ssum[idx];
    }
}

// reads u from uy16, overwrites it with y; h0 from Psum (in-place), dl from Dbuf
__global__ __launch_bounds__(256) void scan_phaseC(
    bf16* __restrict__ uy16, const bf16* __restrict__ xz16,
    const float* __restrict__ xdbl,
    const float* __restrict__ A_log, const float* __restrict__ D_skip,
    const float* __restrict__ H0, const float* __restrict__ Dbuf) {
    int gtid = blockIdx.x * 256 + threadIdx.x;
    int d = gtid % DINNER;
    int c = (gtid / DINNER) % NCHUNK;
    int b = gtid / (DINNER * NCHUNK);
    float Av[DSTATE], h[DSTATE];
    size_t base = ((size_t)(b * NCHUNK + c) * DSTATE) * DINNER + d;
    #pragma unroll
    for (int s = 0; s < DSTATE; ++s) {
        Av[s] = -__expf(A_log[d * DSTATE + s]);
        h[s] = H0[base + (size_t)s * DINNER];
    }
    float Dsk = D_skip[d];
    int t0 = c * CLEN;
    int rowb = b * LSEQ;
    for (int i = 0; i < CLEN; ++i) {
        int row = rowb + t0 + i;
        const float* xrow = xdbl + (size_t)row * XDSTR;
        float dl = Dbuf[(size_t)row * DINNER + d];
        float u = __bfloat162float(uy16[(size_t)row * DINNER + d]);
        float bt = dl * u;
        const float4* Bp = (const float4*)(xrow + DTRANK);
        float4 B0 = Bp[0], B1 = Bp[1], B2 = Bp[2], B3 = Bp[3];
        const float4* Cp = (const float4*)(xrow + DTRANK + DSTATE);
        float4 C0 = Cp[0], C1 = Cp[1], C2 = Cp[2], C3 = Cp[3];
        float Bv[DSTATE] = {B0.x,B0.y,B0.z,B0.w, B1.x,B1.y,B1.z,B1.w,
                            B2.x,B2.y,B2.z,B2.w, B3.x,B3.y,B3.z,B3.w};
        float Cv[DSTATE] = {C0.x,C0.y,C0.z,C0.w, C1.x,C1.y,C1.z,C1.w,
                            C2.x,C2.y,C2.z,C2.w, C3.x,C3.y,C3.z,C3.w};
        float acc = 0.f;
        #pragma unroll
        for (int s = 0; s < DSTATE; ++s) {
            float a = __expf(dl * Av[s]);
            h[s] = a * h[s] + bt * Bv[s];
            acc += h[s] * Cv[s];
        }
        float zv = __bfloat162float(xz16[(size_t)row * XZLD + DINNER + d]);
        float sz = zv / (1.f + __expf(-zv));
        uy16[(size_t)row * DINNER + d] = __float2bfloat16((acc + u * Dsk) * sz);
    }
}

// ---------------- final: last-token rmsnorm over res + P0..P3 ----------------
__global__ __launch_bounds__(256) void final_acc_kernel(
    const float* __restrict__ res, const float* __restrict__ p0, const float* __restrict__ p1,
    const float* __restrict__ p2, const float* __restrict__ p3,
    const int* __restrict__ mask, const float* __restrict__ w, float* __restrict__ out) {
    __shared__ float sbuf[8];
    int b = blockIdx.x;
    float cnt = 0.f;
    for (int i = threadIdx.x; i < LSEQ; i += 256) cnt += (float)mask[b * LSEQ + i];
    cnt = block_reduce_sum(cnt, sbuf);
    int last = (int)cnt - 1;
    size_t base = ((size_t)b * LSEQ + last) * DMODEL;
    float ss = 0.f;
    for (int i = threadIdx.x; i < DMODEL; i += 256) {
        float v = res[base + i] + ((p0[base + i] + p1[base + i]) + (p2[base + i] + p3[base + i]));
        ss += v * v;
    }
    ss = block_reduce_sum(ss, sbuf);
    float scale = rsqrtf(ss / (float)DMODEL + 1e-5f);
    for (int i = threadIdx.x; i < DMODEL; i += 256) {
        float v = res[base + i] + ((p0[base + i] + p1[base + i]) + (p2[base + i] + p3[base + i]));
        out[b * DMODEL + i] = v * scale * w[i];
    }
}

extern "C" void kernel_launch(void* const* d_in, const int* in_sizes, int n_in,
                              void* d_out, int out_size, void* d_ws, size_t ws_size,
                              hipStream_t stream) {
    const int*   seq      = (const int*)d_in[0];
    const int*   mask     = (const int*)d_in[1];
    const float* emb      = (const float*)d_in[2];
    const float* norm_w   = (const float*)d_in[3];
    const float* in_w     = (const float*)d_in[4];
    const float* conv_w   = (const float*)d_in[5];
    const float* conv_b   = (const float*)d_in[6];
    const float* xp_w     = (const float*)d_in[7];
    const float* dt_w     = (const float*)d_in[8];
    const float* dt_b     = (const float*)d_in[9];
    const float* A_log    = (const float*)d_in[10];
    const float* D_skip   = (const float*)d_in[11];
    const float* out_w    = (const float*)d_in[12];
    const float* normf_w  = (const float*)d_in[13];
    float* out = (float*)d_out;

    char* ws = (char*)d_ws;
    float* residual = (float*)(ws);                      //  6,291,456
    bf16*  hn16     = (bf16*)(ws + 6291456);             //  3,145,728
    bf16*  xz16     = (bf16*)(ws + 9437184);             // 12,582,912
    float* xdbl     = (float*)(ws + 22020096);           //  2,097,152 (2 buffers)
    bf16*  uy16     = (bf16*)(ws + 24117248);            //  6,291,456 (u, then y in-place)
    float* Psum     = (float*)(ws + 30408704);           // 12,582,912 (P, then h0, then P0/P1)
    float* Ssum     = (float*)(ws + 42991616);           // 12,582,912 (S, then P2/P3)
    float* Dbuf     = (float*)(ws + 55574528);           // 12,582,912 (delta; ex-Hin)
    bf16*  in16     = (bf16*)(ws + 68157440);            // 18,874,368
    bf16*  out16    = (bf16*)(ws + 87031808);            //  9,437,184
    bf16*  xp16     = (bf16*)(ws + 96468992);            //  1,572,864
                                                         // total 98,041,856 bytes
    // out_proj partials: 4 x 6,291,456 B carved from Psum/Ssum (dead after scanC)
    float* P0 = Psum;
    float* P1 = Psum + (size_t)BSZ * LSEQ * DMODEL;      // 1,572,864 floats
    float* P2 = Ssum;
    float* P3 = Ssum + (size_t)BSZ * LSEQ * DMODEL;

    init_kernel<<<66560, 256, 0, stream>>>(seq, emb, in_w, out_w, xp_w,
                                           residual, in16, out16, xp16, xdbl);

    for (int i = 0; i < NLAYER; ++i) {
        float* xd_cur = xdbl + (size_t)(i & 1) * (BSZ * LSEQ * XDSTR);
        float* xd_nxt = xdbl + (size_t)((i + 1) & 1) * (BSZ * LSEQ * XDSTR);
        const float* cw = conv_w + (size_t)i * DINNER * DCONV;
        const float* cb = conv_b + (size_t)i * DINNER;
        const float* dw = dt_w + (size_t)i * DINNER * DTRANK;
        const float* db = dt_b + (size_t)i * DINNER;
        const float* al = A_log + (size_t)i * DINNER * DSTATE;

        if (i == 0)
            rmsnorm_kernel<<<BSZ * LSEQ, 256, 0, stream>>>(
                residual, norm_w, hn16);
        else
            rmsnorm_acc_kernel<<<BSZ * LSEQ, 256, 0, stream>>>(
                residual, P0, P1, P2, P3, norm_w + (size_t)i * DMODEL, hn16);
        // in_proj: xz16(2048x3072) = hn16 @ in16[i]^T  (grid 768, 3 blocks/CU)
        gemm_128x64_g<<<dim3(16, 48), 256, 0, stream>>>(
            hn16, DMODEL, in16 + (size_t)i * 3072 * DMODEL, DMODEL, xz16, XZLD, DMODEL);
        // u = silu(conv(x)+cb): throughput kernel, writes uy16
        usilu_kernel<<<(BSZ * LSEQ * UCHUNKS) / 256, 256, 0, stream>>>(xz16, cw, cb, uy16);
        // x_proj: xdbl(2048x128) f32 = u @ xp16[i]^T, split-K=8 atomic (grid 512)
        gemm_64_atomic_g<<<dim3(32, 2, 8), 256, 0, stream>>>(
            uy16, DINNER, xp16 + (size_t)i * 128 * DINNER, DINNER, xd_cur, XDSTR, DINNER);
        scan_phaseA<<<768, 256, 0, stream>>>(
            uy16, xd_cur, dw, db, al, Psum, Ssum, Dbuf, xd_nxt);
        scan_phaseB<<<192, 256, 0, stream>>>(Psum, Ssum);
        scan_phaseC<<<768, 256, 0, stream>>>(
            uy16, xz16, xd_cur, al, D_skip + (size_t)i * DINNER, Psum, Dbuf);
        // out_proj partials: P0..P3(2048x768) = y @ out16[i]^T, 128x64 tile, split-K=4
        gemm_128x64_part_g<<<dim3(16, 12, 4), 256, 0, stream>>>(
            uy16, DINNER, out16 + (size_t)i * DMODEL * DINNER, DINNER,
            P0, P1, P2, P3, DMODEL, DINNER);
    }

    final_acc_kernel<<<BSZ, 256, 0, stream>>>(residual, P0, P1, P2, P3, mask, normf_w, out);
}